// Round 3
// baseline (1589.260 us; speedup 1.0000x reference)
//
#include <hip/hip_runtime.h>

typedef unsigned short u16;
typedef __bf16 bf16x8 __attribute__((ext_vector_type(8)));
typedef float floatx4 __attribute__((ext_vector_type(4)));

__device__ inline u16 f2bf(float f) {
    return __builtin_bit_cast(u16, (__bf16)f);   // v_cvt RNE, 1 op
}
__device__ inline float bf2f(u16 h) {
    return __uint_as_float(((unsigned int)h) << 16);
}

// async global->LDS, 16B per lane. LDS dest must be wave-uniform base + lane*16.
__device__ __forceinline__ void async_copy16(u16* lds, const u16* g) {
    __builtin_amdgcn_global_load_lds(
        (const __attribute__((address_space(1))) unsigned int*)(uintptr_t)g,
        (__attribute__((address_space(3))) unsigned int*)(unsigned int)(uintptr_t)lds,
        16, 0, 0);
}

// ---------------------------------------------------------------------------
// zero ONLY the 1-px halo ring of a padded NHWC buffer [512][Hp][Hp][C]
// ---------------------------------------------------------------------------
__global__ void zero_halo(u16* __restrict__ buf, int Hp, int C, int total8)
{
    int i = blockIdx.x * 256 + threadIdx.x;
    if (i >= total8) return;
    int c8 = i % (C / 8);
    int p  = i / (C / 8);
    int ring = 4 * Hp - 4;
    int h = p % ring;
    int b = p / ring;
    int y, x;
    if (h < Hp)              { y = 0;              x = h; }
    else if (h < 2 * Hp)     { y = Hp - 1;         x = h - Hp; }
    else if (h < 3 * Hp - 2) { y = h - 2 * Hp + 1; x = 0; }
    else                     { y = h - 3 * Hp + 3; x = Hp - 1; }
    uint4 z = make_uint4(0u, 0u, 0u, 0u);
    *(uint4*)(buf + ((size_t)((b * Hp + y) * Hp + x) * C) + c8 * 8) = z;
}

// ---------------------------------------------------------------------------
// Layer 0: direct conv 3->64, 32x32, output PADDED NHWC [512][34][34][64]
// ---------------------------------------------------------------------------
__global__ __launch_bounds__(256) void conv0_kernel(
    const float* __restrict__ x, const float* __restrict__ w,
    const float* __restrict__ bias, u16* __restrict__ out)
{
    __shared__ __align__(16) float xs[3][6][36];
    const int t  = threadIdx.x;
    const int b  = blockIdx.x >> 3;
    const int y0 = (blockIdx.x & 7) * 4;

    for (int i = t; i < 3 * 6 * 36; i += 256) {
        int ci  = i / 216;
        int rem = i % 216;
        int r   = rem / 36;
        int c   = rem % 36;
        int gy  = y0 - 1 + r;
        int gx  = c - 1;
        float v = 0.f;
        if ((unsigned)gy < 32u && (unsigned)gx < 32u)
            v = x[((b * 3 + ci) * 32 + gy) * 32 + gx];
        xs[ci][r][c] = v;
    }
    const int lane = t & 63;
    const int wv   = t >> 6;
    float wr[27];
    #pragma unroll
    for (int k = 0; k < 27; k++) wr[k] = w[lane * 27 + k];
    const float bz = bias[lane];
    __syncthreads();

    const int y = y0 + wv;
    u16* orow = out + ((size_t)((b * 34 + y + 1) * 34 + 1) * 64) + lane;
    for (int xg = 0; xg < 32; xg += 4) {
        float a0 = bz, a1 = bz, a2 = bz, a3 = bz;
        #pragma unroll
        for (int ci = 0; ci < 3; ci++) {
            #pragma unroll
            for (int rr = 0; rr < 3; rr++) {
                const float* row = &xs[ci][wv + rr][0];
                float4 c03 = *(const float4*)(row + xg);
                float2 c45 = *(const float2*)(row + xg + 4);
                float w0 = wr[ci * 9 + rr * 3 + 0];
                float w1 = wr[ci * 9 + rr * 3 + 1];
                float w2 = wr[ci * 9 + rr * 3 + 2];
                a0 += c03.x * w0 + c03.y * w1 + c03.z * w2;
                a1 += c03.y * w0 + c03.z * w1 + c03.w * w2;
                a2 += c03.z * w0 + c03.w * w1 + c45.x * w2;
                a3 += c03.w * w0 + c45.x * w1 + c45.y * w2;
            }
        }
        orow[(xg + 0) * 64] = f2bf(fmaxf(a0, 0.f));
        orow[(xg + 1) * 64] = f2bf(fmaxf(a1, 0.f));
        orow[(xg + 2) * 64] = f2bf(fmaxf(a2, 0.f));
        orow[(xg + 3) * 64] = f2bf(fmaxf(a3, 0.f));
    }
}

// ---------------------------------------------------------------------------
// Merged weight repack, LDS-staged so BOTH global sides are coalesced.
// ---------------------------------------------------------------------------
struct RepackArgs {
    const float* src[14];
    u16* dst[14];
    int p1[14];        // Cin (conv) or K (lin)
    int p2[14];        // 0 (conv) or N (lin)
    int startBlk[15];
    int nseg;
};

__global__ __launch_bounds__(256) void repack_all(RepackArgs a)
{
    __shared__ __align__(16) u16 lds[9216];
    int blk = blockIdx.x;
    int s = 0;
    #pragma unroll 1
    while (s + 1 < a.nseg && blk >= a.startBlk[s + 1]) s++;
    const int cb = blk - a.startBlk[s];
    const int t  = threadIdx.x;

    if (a.p2[s] == 0) {
        // ---- conv: block covers 9216 consecutive elements of src AND dst ----
        const int Cin = a.p1[s];
        const int logCin = __builtin_ctz(Cin);
        const float* src = a.src[s] + (size_t)cb * 9216;
        u16* dst = a.dst[s] + (size_t)cb * 9216;
        #pragma unroll
        for (int it = 0; it < 9; it++) {
            int j4 = it * 256 + t;                       // float4 index 0..2303
            float4 v = *(const float4*)(src + j4 * 4);
            ushort4 h;
            h.x = f2bf(v.x); h.y = f2bf(v.y); h.z = f2bf(v.z); h.w = f2bf(v.w);
            *(ushort4*)(lds + j4 * 4) = h;
        }
        __syncthreads();
        #pragma unroll
        for (int it = 0; it < 9; it++) {
            int o4   = (it * 256 + t) * 4;               // dst linear (co*9+sh)*Cin+ci
            int ci   = o4 & (Cin - 1);
            int rest = o4 >> logCin;                     // co*9 + sh
            int co   = rest / 9;
            int sh   = rest - co * 9;
            int sb   = (co << logCin) * 9 + ci * 9 + sh; // src-order LDS index
            ushort4 h;
            h.x = lds[sb]; h.y = lds[sb + 9]; h.z = lds[sb + 18]; h.w = lds[sb + 27];
            *(ushort4*)(dst + o4) = h;
        }
    } else {
        // ---- linear: 64x64 tile transpose f32[K][N] -> bf16[N][K] ----
        const int K = a.p1[s], N = a.p2[s];
        const int ntx = N >> 6;
        const int k0 = (cb / ntx) * 64, n0 = (cb % ntx) * 64;
        const float* src = a.src[s];
        u16* dst = a.dst[s];
        const int r = t >> 4, c4 = (t & 15) * 4;         // lds pitch 72 u16
        #pragma unroll
        for (int rr = 0; rr < 64; rr += 16) {
            float4 v = *(const float4*)(src + (size_t)(k0 + r + rr) * N + n0 + c4);
            u16* p = lds + (r + rr) * 72 + c4;
            p[0] = f2bf(v.x); p[1] = f2bf(v.y); p[2] = f2bf(v.z); p[3] = f2bf(v.w);
        }
        __syncthreads();
        #pragma unroll
        for (int it = 0; it < 2; it++) {
            int ov = it * 256 + t;                       // 0..511 output vec8s
            int n  = ov >> 3;
            int kq = (ov & 7) * 8;
            __align__(16) u16 h[8];
            #pragma unroll
            for (int j = 0; j < 8; j++) h[j] = lds[(kq + j) * 72 + n];
            *(uint4*)(dst + (size_t)(n0 + n) * K + k0 + kq) = *(uint4*)h;
        }
    }
}

// ---------------------------------------------------------------------------
// Conv shift-GEMM, bf16 MFMA 16x16x32.
// A-fragments are loaded DIRECTLY from global (NHWC makes the 16x32 fragment a
// dense, 16B-aligned per-lane load; input is L2/L3-hot across taps) — no A-LDS.
// Only B (weights) is LDS-staged, double-buffered, XOR-8 swizzle via source
// permutation. LDS drops to 16/32 KB -> 5-8 blocks/CU for latency hiding.
// BM=128: 4 waves 2x2 (wave cols = BN/2). BM=256: 4 waves 4x1 (wave cols = BN).
// ---------------------------------------------------------------------------
template <int BM, int BN>
__global__ __launch_bounds__(256, 8) void conv_gemm(
    const u16* __restrict__ in, const u16* __restrict__ wt,
    const float* __restrict__ bias, u16* __restrict__ out,
    float* __restrict__ partial, size_t pstride,
    int H, int Cin, int Cout, int logHW, int logW, int splitN,
    int outPad, int poolMode)
{
    constexpr int BK = 64;
    constexpr int WC = (BM == 256) ? BN : (BN / 2);   // wave cols
    constexpr int NT = WC / 16;
    constexpr int NB_B = BN / 32;
    constexpr int BSZ = BN * BK;
    __shared__ u16 Bs[2 * BSZ];

    const int Nblocks = Cout / BN;
    const int per = gridDim.x >> 3;
    const int bid = (blockIdx.x & 7) * per + (blockIdx.x >> 3);
    const int sp   = bid % splitN;
    const int tile = bid / splitN;
    const int m0 = (tile / Nblocks) * BM;
    const int n0 = (tile % Nblocks) * BN;

    const int t    = threadIdx.x;
    const int lane = t & 63;
    const int wave = t >> 6;
    const int quad = lane >> 4;
    const int l16  = lane & 15;
    const int wm   = (BM == 256) ? wave : (wave >> 1);
    const int wn   = (BM == 256) ? 0 : (wave & 1);
    const int W    = H;
    const int Wp   = H + 2;
    const int HW   = 1 << logHW;
    const int col8 = t & 7;
    const int r0   = t >> 3;
    const int scol = col8 ^ (r0 & 7);

    const int CinB = Cin * 2;

    // per-thread A fragment base (bytes): padded-pixel addr + quad channel chunk
    int aBase[4];
    #pragma unroll
    for (int mt = 0; mt < 4; mt++) {
        int m  = m0 + wm * 64 + mt * 16 + l16;
        int b  = m >> logHW;
        int rm = m & (HW - 1);
        int y  = rm >> logW;
        int xx = rm & (W - 1);
        aBase[mt] = ((b * Wp + y + 1) * Wp + xx + 1) * CinB + quad * 16;
    }
    int vB[NB_B];
    #pragma unroll
    for (int j = 0; j < NB_B; j++)
        vB[j] = (n0 + r0 + 32 * j) * 9 * CinB + scol * 16;

    const int logKB = (Cin == 64) ? 0 : (Cin == 128) ? 1 : (Cin == 256) ? 2 : 3;
    const int KB  = 1 << logKB;
    const int T   = 9 * KB;
    const int len = T / splitN;
    const int it0 = sp * len;

    int s0 = it0 >> logKB;
    int c3 = s0 - (s0 / 3) * 3;
    int ta = ((s0 / 3 - 1) * Wp + (c3 - 1)) * CinB;
    int kb = (it0 & (KB - 1)) * 128;
    int tb = it0 * 128;

    const char* const inB = (const char*)in;
    const char* const wtB = (const char*)wt;

    floatx4 acc[4][NT];
    #pragma unroll
    for (int i = 0; i < 4; i++)
        #pragma unroll
        for (int j = 0; j < NT; j++)
            acc[i][j] = (floatx4){0.f, 0.f, 0.f, 0.f};

    const int sw = (l16 & 7) * 8;

    auto stageB = [&](int tbv, int buf) {
        u16* lb = Bs + buf * BSZ + t * 8;
        #pragma unroll
        for (int j = 0; j < NB_B; j++)
            async_copy16(lb + j * 2048, (const u16*)(wtB + (tbv + vB[j])));
    };

    // prologue: stage B(0) into buf 0
    stageB(tb, 0);
    tb += 128;
    __syncthreads();                       // implicit vmcnt(0): buf0 ready

    int cur = 0;
    for (int it = 0; it < len; it++) {
        if (it + 1 < len) {                // prefetch next B tile
            stageB(tb, cur ^ 1);
            tb += 128;
        }
        const int offs = ta + kb;          // A byte offset for THIS iter
        kb += 128;
        if (kb == CinB) {
            kb = 0;
            ta += (c3 == 2) ? (Wp - 2) * CinB : CinB;
            c3 = (c3 == 2) ? 0 : c3 + 1;
        }

        // A fragments straight from global (L2/L3-hot)
        bf16x8 af[2][4];
        #pragma unroll
        for (int kk2 = 0; kk2 < 2; kk2++)
            #pragma unroll
            for (int mt = 0; mt < 4; mt++)
                af[kk2][mt] = *(const bf16x8*)(inB + (offs + aBase[mt] + kk2 * 64));

        const u16* Bb = Bs + cur * BSZ;
        #pragma unroll
        for (int kk2 = 0; kk2 < 2; kk2++) {
            int cbo = kk2 * 32 + quad * 8;
            bf16x8 bfv[NT];
            #pragma unroll
            for (int nt = 0; nt < NT; nt++)
                bfv[nt] = *(const bf16x8*)(Bb + (wn * WC + nt * 16 + l16) * 64 + (cbo ^ sw));
            #pragma unroll
            for (int mt = 0; mt < 4; mt++)
                #pragma unroll
                for (int nt = 0; nt < NT; nt++)
                    acc[mt][nt] = __builtin_amdgcn_mfma_f32_16x16x32_bf16(
                        af[kk2][mt], bfv[nt], acc[mt][nt], 0, 0, 0);
        }
        __syncthreads();                   // prefetch done + all reads of cur done
        cur ^= 1;
    }

    const int ngb = n0 + wn * WC + l16;

    if (splitN > 1) {
        float* pout = partial + (size_t)sp * pstride;
        #pragma unroll
        for (int mt = 0; mt < 4; mt++)
            #pragma unroll
            for (int r = 0; r < 4; r++) {
                int mg = m0 + wm * 64 + mt * 16 + quad * 4 + r;
                float* op = pout + (size_t)mg * Cout + ngb;
                #pragma unroll
                for (int nt = 0; nt < NT; nt++)
                    op[nt * 16] = acc[mt][nt][r];
            }
        return;
    }

    float bzv[NT];
    #pragma unroll
    for (int nt = 0; nt < NT; nt++) bzv[nt] = bias[ngb + nt * 16];

    if (poolMode) {
        const int Hpo = (H >> 1) + 2;
        if (logW == 5) {            // W=32: y-partner = mt+2, in-lane
            #pragma unroll
            for (int mt = 0; mt < 2; mt++)
                #pragma unroll
                for (int rp = 0; rp < 2; rp++) {
                    int m1 = m0 + wm * 64 + mt * 16 + quad * 4 + 2 * rp;
                    int b  = m1 >> logHW;
                    int rm = m1 & (HW - 1);
                    int yp = (rm >> logW) >> 1;
                    int xp = (rm & (W - 1)) >> 1;
                    u16* op = out + (size_t)((b * Hpo + yp + 1) * Hpo + xp + 1) * Cout + ngb;
                    #pragma unroll
                    for (int nt = 0; nt < NT; nt++) {
                        float v = fmaxf(
                            fmaxf(acc[mt][nt][2 * rp], acc[mt][nt][2 * rp + 1]),
                            fmaxf(acc[mt + 2][nt][2 * rp], acc[mt + 2][nt][2 * rp + 1]));
                        op[nt * 16] = f2bf(fmaxf(v + bzv[nt], 0.f));
                    }
                }
        } else if (logW == 4) {     // W=16: y-partner = mt+1, in-lane
            #pragma unroll
            for (int mtp = 0; mtp < 2; mtp++)
                #pragma unroll
                for (int rp = 0; rp < 2; rp++) {
                    int mt = 2 * mtp;
                    int m1 = m0 + wm * 64 + mt * 16 + quad * 4 + 2 * rp;
                    int b  = m1 >> logHW;
                    int rm = m1 & (HW - 1);
                    int yp = (rm >> logW) >> 1;
                    int xp = (rm & (W - 1)) >> 1;
                    u16* op = out + (size_t)((b * Hpo + yp + 1) * Hpo + xp + 1) * Cout + ngb;
                    #pragma unroll
                    for (int nt = 0; nt < NT; nt++) {
                        float v = fmaxf(
                            fmaxf(acc[mt][nt][2 * rp], acc[mt][nt][2 * rp + 1]),
                            fmaxf(acc[mt + 1][nt][2 * rp], acc[mt + 1][nt][2 * rp + 1]));
                        op[nt * 16] = f2bf(fmaxf(v + bzv[nt], 0.f));
                    }
                }
        } else {                    // W=8: y-partner = quad+2 via shfl32
            #pragma unroll
            for (int mt = 0; mt < 4; mt++)
                #pragma unroll
                for (int rp = 0; rp < 2; rp++) {
                    int m1 = m0 + wm * 64 + mt * 16 + quad * 4 + 2 * rp;
                    int b  = m1 >> logHW;
                    int rm = m1 & (HW - 1);
                    int yp = (rm >> logW) >> 1;
                    int xp = (rm & (W - 1)) >> 1;
                    u16* op = out + (size_t)((b * Hpo + yp + 1) * Hpo + xp + 1) * Cout + ngb;
                    #pragma unroll
                    for (int nt = 0; nt < NT; nt++) {
                        float a = fmaxf(acc[mt][nt][2 * rp], acc[mt][nt][2 * rp + 1]);
                        float p = __shfl_xor(a, 32, 64);
                        float v = fmaxf(a, p);
                        if (quad < 2)
                            op[nt * 16] = f2bf(fmaxf(v + bzv[nt], 0.f));
                    }
                }
        }
        return;
    }

    #pragma unroll
    for (int mt = 0; mt < 4; mt++) {
        #pragma unroll
        for (int r = 0; r < 4; r++) {
            int mg = m0 + wm * 64 + mt * 16 + quad * 4 + r;
            size_t obase;
            if (outPad) {
                int b  = mg >> logHW;
                int rm = mg & (HW - 1);
                int y  = rm >> logW;
                int xx = rm & (W - 1);
                obase = (size_t)((b * Wp + y + 1) * Wp + xx + 1) * Cout;
            } else {
                obase = (size_t)mg * Cout;
            }
            u16* op = out + obase + ngb;
            #pragma unroll
            for (int nt = 0; nt < NT; nt++)
                op[nt * 16] = f2bf(fmaxf(acc[mt][nt][r] + bzv[nt], 0.f));
        }
    }
}

// sum split partials + bias + relu -> bf16 NHWC (padded out optional)
__global__ void reduce_split(const float* __restrict__ partial,
                             const float* __restrict__ bias, u16* __restrict__ out,
                             int MN, int C, int logC, int splitN, size_t pstride,
                             int H, int logHW, int logW, int outPad)
{
    int i4 = (blockIdx.x * 256 + threadIdx.x) * 4;
    if (i4 >= MN) return;
    float4 s = *(const float4*)(partial + i4);
    for (int sp = 1; sp < splitN; sp++) {
        float4 p = *(const float4*)(partial + (size_t)sp * pstride + i4);
        s.x += p.x; s.y += p.y; s.z += p.z; s.w += p.w;
    }
    int n = i4 & (C - 1);
    int m = i4 >> logC;
    size_t obase;
    if (outPad) {
        int Wp = H + 2;
        int b  = m >> logHW;
        int rm = m & ((1 << logHW) - 1);
        int y  = rm >> logW;
        int xx = rm & (H - 1);
        obase = (size_t)((b * Wp + y + 1) * Wp + xx + 1) * C;
    } else {
        obase = (size_t)m * C;
    }
    ushort4 o;
    o.x = f2bf(fmaxf(s.x + bias[n + 0], 0.f));
    o.y = f2bf(fmaxf(s.y + bias[n + 1], 0.f));
    o.z = f2bf(fmaxf(s.z + bias[n + 2], 0.f));
    o.w = f2bf(fmaxf(s.w + bias[n + 3], 0.f));
    *(ushort4*)(out + obase + n) = o;
}

// sum split partials + bias + relu + 2x2 maxpool -> bf16 (padded optional)
__global__ void reduce_pool(const float* __restrict__ partial,
                            const float* __restrict__ bias, u16* __restrict__ out,
                            int total4, int C, int splitN, size_t pstride,
                            int H, int outPad)
{
    int idx = blockIdx.x * 256 + threadIdx.x;
    if (idx >= total4) return;
    int c4 = idx % (C / 4);
    int p  = idx / (C / 4);
    int Ho = H >> 1;
    int xp = p % Ho; p /= Ho;
    int yp = p % Ho;
    int b  = p / Ho;
    int n  = c4 * 4;
    float4 best;
    bool first = true;
    #pragma unroll
    for (int dy = 0; dy < 2; dy++)
        #pragma unroll
        for (int dx = 0; dx < 2; dx++) {
            int m = (b * H + 2 * yp + dy) * H + 2 * xp + dx;
            const float* q = partial + (size_t)m * C + n;
            float4 s = *(const float4*)q;
            for (int sp = 1; sp < splitN; sp++) {
                float4 pp = *(const float4*)(q + (size_t)sp * pstride);
                s.x += pp.x; s.y += pp.y; s.z += pp.z; s.w += pp.w;
            }
            if (first) { best = s; first = false; }
            else {
                best.x = fmaxf(best.x, s.x); best.y = fmaxf(best.y, s.y);
                best.z = fmaxf(best.z, s.z); best.w = fmaxf(best.w, s.w);
            }
        }
    size_t obase;
    if (outPad) {
        int Hpo = Ho + 2;
        obase = (size_t)((b * Hpo + yp + 1) * Hpo + xp + 1) * C;
    } else {
        obase = (size_t)((b * Ho + yp) * Ho + xp) * C;
    }
    ushort4 o;
    o.x = f2bf(fmaxf(best.x + bias[n + 0], 0.f));
    o.y = f2bf(fmaxf(best.y + bias[n + 1], 0.f));
    o.z = f2bf(fmaxf(best.z + bias[n + 2], 0.f));
    o.w = f2bf(fmaxf(best.w + bias[n + 3], 0.f));
    *(ushort4*)(out + obase + n) = o;
}

// ---------------------------------------------------------------------------
// Generic small GEMM: out[M,N] = act(A[M,K](bf16) @ Bt[N,K](bf16)^T + bias)
// ---------------------------------------------------------------------------
template <bool RELU, bool OUTBF>
__global__ __launch_bounds__(256) void gemm64(
    const u16* __restrict__ A, const u16* __restrict__ Bt,
    const float* __restrict__ bias, void* __restrict__ outv,
    int M, int N, int K)
{
    constexpr int LDP = 72;
    __shared__ u16 As[64 * LDP];
    __shared__ u16 Bs[64 * LDP];

    const int nb = N >> 6;
    const int m0 = (blockIdx.x / nb) * 64;
    const int n0 = (blockIdx.x % nb) * 64;
    const int t = threadIdx.x, lane = t & 63, wave = t >> 6;
    const int quad = lane >> 4, l16 = lane & 15;
    const int wm = wave >> 1, wn = wave & 1;
    const int col8 = t & 7, r0 = t >> 3;

    floatx4 acc[2][2];
    #pragma unroll
    for (int i = 0; i < 2; i++)
        #pragma unroll
        for (int j = 0; j < 2; j++)
            acc[i][j] = (floatx4){0.f, 0.f, 0.f, 0.f};

    for (int kb = 0; kb < K; kb += 64) {
        #pragma unroll
        for (int j = 0; j < 2; j++) {
            int row = r0 + 32 * j;
            *(uint4*)(As + row * LDP + col8 * 8) =
                *(const uint4*)(A + (size_t)(m0 + row) * K + kb + col8 * 8);
            *(uint4*)(Bs + row * LDP + col8 * 8) =
                *(const uint4*)(Bt + (size_t)(n0 + row) * K + kb + col8 * 8);
        }
        __syncthreads();
        #pragma unroll
        for (int kk = 0; kk < 64; kk += 32) {
            bf16x8 af[2], bfv[2];
            #pragma unroll
            for (int mt = 0; mt < 2; mt++)
                af[mt] = *(const bf16x8*)(As + (wm * 32 + mt * 16 + l16) * LDP + kk + quad * 8);
            #pragma unroll
            for (int nt = 0; nt < 2; nt++)
                bfv[nt] = *(const bf16x8*)(Bs + (wn * 32 + nt * 16 + l16) * LDP + kk + quad * 8);
            #pragma unroll
            for (int mt = 0; mt < 2; mt++)
                #pragma unroll
                for (int nt = 0; nt < 2; nt++)
                    acc[mt][nt] = __builtin_amdgcn_mfma_f32_16x16x32_bf16(
                        af[mt], bfv[nt], acc[mt][nt], 0, 0, 0);
        }
        __syncthreads();
    }
    #pragma unroll
    for (int mt = 0; mt < 2; mt++) {
        #pragma unroll
        for (int nt = 0; nt < 2; nt++) {
            #pragma unroll
            for (int r = 0; r < 4; r++) {
                int mg = m0 + wm * 32 + mt * 16 + quad * 4 + r;
                int ng = n0 + wn * 32 + nt * 16 + l16;
                float v = acc[mt][nt][r] + bias[ng];
                if (RELU) v = fmaxf(v, 0.f);
                if (OUTBF) ((u16*)outv)[(size_t)mg * N + ng] = f2bf(v);
                else       ((float*)outv)[(size_t)mg * N + ng] = v;
            }
        }
    }
}

// ---------------------------------------------------------------------------
__global__ __launch_bounds__(256) void graph_tile(
    const float* __restrict__ low, const int* __restrict__ target,
    float* __restrict__ gpre, float* __restrict__ ggt)
{
    __shared__ float Al[64 * 132];
    __shared__ float Bl[128 * 68];
    const int t = threadIdx.x;
    const int gr0 = (blockIdx.x >> 3) * 64;
    const int gc0 = (blockIdx.x & 7) * 64;

    #pragma unroll
    for (int j = 0; j < 32; j++) {
        int flat = t + 256 * j;
        int k = flat & 127;
        int rc = flat >> 7;
        Al[rc * 132 + k] = low[(size_t)(gr0 + rc) * 128 + k];
        Bl[k * 68 + rc]  = low[(size_t)(gc0 + rc) * 128 + k];
    }
    __syncthreads();

    const int tx = t & 15, ty = t >> 4;
    float acc[4][4];
    #pragma unroll
    for (int r = 0; r < 4; r++)
        #pragma unroll
        for (int c = 0; c < 4; c++) acc[r][c] = 0.f;

    for (int k = 0; k < 128; k++) {
        float a[4], b[4];
        #pragma unroll
        for (int r = 0; r < 4; r++) a[r] = Al[(ty * 4 + r) * 132 + k];
        #pragma unroll
        for (int c = 0; c < 4; c++) b[c] = Bl[k * 68 + tx * 4 + c];
        #pragma unroll
        for (int r = 0; r < 4; r++)
            #pragma unroll
            for (int c = 0; c < 4; c++) acc[r][c] += a[r] * b[c];
    }
    #pragma unroll
    for (int r = 0; r < 4; r++) {
        int row = gr0 + ty * 4 + r;
        int tr  = target[row];
        float4 gp, gg;
        float* pp = (float*)&gp;
        float* gg_ = (float*)&gg;
        #pragma unroll
        for (int c = 0; c < 4; c++) {
            pp[c]  = 1.f / (1.f + __expf(-acc[r][c]));
            gg_[c] = (tr == target[gc0 + tx * 4 + c]) ? 1.f : 0.f;
        }
        *(float4*)(gpre + (size_t)row * 512 + gc0 + tx * 4) = gp;
        *(float4*)(ggt  + (size_t)row * 512 + gc0 + tx * 4) = gg;
    }
}

// ---------------------------------------------------------------------------
__global__ __launch_bounds__(256) void cls_kernel(
    const u16* __restrict__ feat, const float* __restrict__ w,
    const float* __restrict__ bias, float* __restrict__ out)
{
    __shared__ float ws[5120];
    const int t = threadIdx.x;
    for (int i = t; i < 5120; i += 256) ws[i] = w[i];
    __syncthreads();
    const int lane = t & 63;
    const int row  = blockIdx.x * 4 + (t >> 6);
    float a[10];
    #pragma unroll
    for (int j = 0; j < 10; j++) a[j] = 0.f;
    #pragma unroll
    for (int i = 0; i < 8; i++) {
        int k = i * 64 + lane;
        float f = bf2f(feat[(size_t)row * 512 + k]);
        #pragma unroll
        for (int j = 0; j < 10; j++) a[j] += f * ws[k * 10 + j];
    }
    #pragma unroll
    for (int j = 0; j < 10; j++)
        #pragma unroll
        for (int off = 32; off > 0; off >>= 1)
            a[j] += __shfl_down(a[j], off, 64);
    if (lane == 0) {
        #pragma unroll
        for (int j = 0; j < 10; j++) out[row * 10 + j] = a[j] + bias[j];
    }
}

// ---------------------------------------------------------------------------
extern "C" void kernel_launch(void* const* d_in, const int* in_sizes, int n_in,
                              void* d_out, int out_size, void* d_ws, size_t ws_size,
                              hipStream_t stream)
{
    const float* x      = (const float*)d_in[0];
    const int*   target = (const int*)d_in[1];
    const float* conv_w[13];
    const float* conv_b[13];
    for (int i = 0; i < 13; i++) {
        conv_w[i] = (const float*)d_in[2 + 2 * i];
        conv_b[i] = (const float*)d_in[3 + 2 * i];
    }
    const float* lin1_w = (const float*)d_in[28];
    const float* lin1_b = (const float*)d_in[29];
    const float* lin2_w = (const float*)d_in[30];
    const float* lin2_b = (const float*)d_in[31];
    const float* cls_w  = (const float*)d_in[32];
    const float* cls_b  = (const float*)d_in[33];
    float* out = (float*)d_out;

    static const int cin_arr[13]  = {3, 64, 64, 128, 128, 256, 256, 256, 512, 512, 512, 512, 512};
    static const int cout_arr[13] = {64, 64, 128, 128, 256, 256, 256, 512, 512, 512, 512, 512, 512};

    char* ws = (char*)d_ws;
    size_t off = 0;
    const size_t R0SZ = (size_t)512 * 34 * 34 * 64 * 2;
    const size_t R1SZ = (size_t)512 * 34 * 34 * 64 * 2;
    char* R0raw = ws + off; off += R0SZ;
    char* R1raw = ws + off; off += R1SZ;
    u16* R0 = (u16*)R0raw;
    u16* R1 = (u16*)R1raw;
    float* PA = (float*)(R0raw + 20971520);
    float* PB = (float*)(R1raw + 20971520);
    u16* wt[13];
    for (int i = 1; i < 13; i++) {
        wt[i] = (u16*)(ws + off);
        off += (size_t)cout_arr[i] * 9 * cin_arr[i] * 2;
    }
    u16* wtl1 = (u16*)(ws + off); off += (size_t)256 * 512 * 2;
    u16* wtl2 = (u16*)(ws + off); off += (size_t)128 * 256 * 2;
    u16* hbuf = (u16*)(ws + off); off += (size_t)512 * 256 * 2;
    float* lowbuf = (float*)(ws + off); off += (size_t)512 * 128 * 4;

    // ---- single merged repack launch (12 conv + 2 lin), LDS-staged ----
    RepackArgs ra;
    int nb = 0, blk = 0;
    ra.startBlk[0] = 0;
    for (int i = 1; i < 13; i++) {
        ra.src[nb] = conv_w[i];
        ra.dst[nb] = wt[i];
        ra.p1[nb] = cin_arr[i];
        ra.p2[nb] = 0;
        blk += cout_arr[i] * cin_arr[i] / 1024;   // 9216 elems per block
        nb++; ra.startBlk[nb] = blk;
    }
    ra.src[nb] = lin1_w; ra.dst[nb] = wtl1; ra.p1[nb] = 512; ra.p2[nb] = 256;
    blk += (512 / 64) * (256 / 64);
    nb++; ra.startBlk[nb] = blk;
    ra.src[nb] = lin2_w; ra.dst[nb] = wtl2; ra.p1[nb] = 256; ra.p2[nb] = 128;
    blk += (256 / 64) * (128 / 64);
    nb++; ra.startBlk[nb] = blk;
    ra.nseg = nb;
    repack_all<<<blk, 256, 0, stream>>>(ra);

    auto zh = [&](u16* buf, int Hp, int C) {
        int total8 = 512 * (4 * Hp - 4) * (C / 8);
        zero_halo<<<(total8 + 255) / 256, 256, 0, stream>>>(buf, Hp, C, total8);
    };
    auto launch_conv = [&](int li, int Hl, int bm, int bn, u16* inb, u16* outb,
                           float* part, int splitN, int outPad, int poolMode) {
        int Cin = cin_arr[li], Cout = cout_arr[li];
        int M = 512 * Hl * Hl;
        int logW = __builtin_ctz(Hl);
        int logHW = 2 * logW;
        size_t pstride = (size_t)M * Cout;
        int grid = (M / bm) * (Cout / bn) * splitN;
        if (bm == 256) {
            conv_gemm<256, 64><<<grid, 256, 0, stream>>>(
                inb, wt[li], conv_b[li], outb, part, pstride,
                Hl, Cin, Cout, logHW, logW, splitN, outPad, poolMode);
        } else if (bn == 128) {
            conv_gemm<128, 128><<<grid, 256, 0, stream>>>(
                inb, wt[li], conv_b[li], outb, part, pstride,
                Hl, Cin, Cout, logHW, logW, splitN, outPad, poolMode);
        } else {
            conv_gemm<128, 64><<<grid, 256, 0, stream>>>(
                inb, wt[li], conv_b[li], outb, part, pstride,
                Hl, Cin, Cout, logHW, logW, splitN, outPad, poolMode);
        }
    };
    auto launch_reduce = [&](int li, int Hl, u16* outb, float* part, int splitN, int outPad) {
        int Cout = cout_arr[li];
        int M = 512 * Hl * Hl;
        int logW = __builtin_ctz(Hl);
        size_t pstride = (size_t)M * Cout;
        int MN = M * Cout;
        reduce_split<<<(MN / 4 + 255) / 256, 256, 0, stream>>>(
            part, conv_b[li], outb, MN, Cout, __builtin_ctz(Cout),
            splitN, pstride, Hl, 2 * logW, logW, outPad);
    };
    auto launch_reduce_pool = [&](int li, int Hl, u16* outb, float* part, int splitN, int outPad) {
        int Cout = cout_arr[li];
        int M = 512 * Hl * Hl;
        size_t pstride = (size_t)M * Cout;
        int total4 = 512 * (Hl / 2) * (Hl / 2) * Cout / 4;
        reduce_pool<<<(total4 + 255) / 256, 256, 0, stream>>>(
            part, conv_b[li], outb, total4, Cout, splitN, pstride, Hl, outPad);
    };

    zh(R0, 34, 64);
    conv0_kernel<<<512 * 8, 256, 0, stream>>>(x, conv_w[0], conv_b[0], R0);

    zh(R1, 18, 64);
    launch_conv(1, 32, 256, 64, R0, R1, nullptr, 1, 0, 1);   // L1 + pool (BM=256)
    zh(R0, 18, 128);
    launch_conv(2, 16, 128, 128, R1, R0, nullptr, 1, 1, 0);  // L2
    zh(R1, 10, 128);
    launch_conv(3, 16, 128, 128, R0, R1, nullptr, 1, 0, 1);  // L3 + pool
    zh(R0, 10, 256);
    launch_conv(4, 8, 128, 128, R1, R0, nullptr, 1, 1, 0);   // L4
    zh(R1, 10, 256);
    launch_conv(5, 8, 128, 128, R0, R1, nullptr, 1, 1, 0);   // L5
    zh(R0, 6, 256);
    launch_conv(6, 8, 128, 128, R1, R0, nullptr, 1, 0, 1);   // L6 + pool
    zh(R1, 6, 512);
    launch_conv(7, 4, 128, 128, R0, R1, PB, 2, 1, 0);        // L7 split2
    launch_reduce(7, 4, R1, PB, 2, 1);
    zh(R0, 6, 512);
    launch_conv(8, 4, 128, 128, R1, R0, PA, 2, 1, 0);        // L8 split2
    launch_reduce(8, 4, R0, PA, 2, 1);
    zh(R1, 4, 512);
    launch_conv(9, 4, 128, 128, R0, R1, PB, 2, 0, 0);        // L9 split2
    launch_reduce_pool(9, 4, R1, PB, 2, 1);
    zh(R0, 4, 512);
    launch_conv(10, 2, 128, 64, R1, R0, PA, 4, 1, 0);        // L10 split4
    launch_reduce(10, 2, R0, PA, 4, 1);
    zh(R1, 4, 512);
    launch_conv(11, 2, 128, 64, R0, R1, PB, 4, 1, 0);        // L11 split4
    launch_reduce(11, 2, R1, PB, 4, 1);
    launch_conv(12, 2, 128, 64, R1, R0, PA, 4, 0, 0);        // L12 split4
    launch_reduce_pool(12, 2, R0, PA, 4, 0);                 // feat = R0 [512,512]

    u16* feat = R0;
    gemm64<true, true><<<(512 / 64) * (256 / 64), 256, 0, stream>>>(
        feat, wtl1, lin1_b, hbuf, 512, 256, 512);
    gemm64<false, false><<<(512 / 64) * (128 / 64), 256, 0, stream>>>(
        hbuf, wtl2, lin2_b, lowbuf, 512, 128, 256);
    graph_tile<<<64, 256, 0, stream>>>(lowbuf, target, out + 5120, out + 5120 + 262144);
    cls_kernel<<<128, 256, 0, stream>>>(feat, cls_w, cls_b, out);
}

// Round 4
// 1045.740 us; speedup vs baseline: 1.5197x; 1.5197x over previous
//
#include <hip/hip_runtime.h>

typedef unsigned short u16;
typedef __bf16 bf16x8 __attribute__((ext_vector_type(8)));
typedef float floatx4 __attribute__((ext_vector_type(4)));

__device__ inline u16 f2bf(float f) {
    return __builtin_bit_cast(u16, (__bf16)f);   // v_cvt RNE, 1 op
}
__device__ inline float bf2f(u16 h) {
    return __uint_as_float(((unsigned int)h) << 16);
}

// async global->LDS, 16B per lane. LDS dest must be wave-uniform base + lane*16.
__device__ __forceinline__ void async_copy16(u16* lds, const u16* g) {
    __builtin_amdgcn_global_load_lds(
        (const __attribute__((address_space(1))) unsigned int*)(uintptr_t)g,
        (__attribute__((address_space(3))) unsigned int*)(unsigned int)(uintptr_t)lds,
        16, 0, 0);
}

// ---------------------------------------------------------------------------
// zero ONLY the 1-px halo ring of a padded NHWC buffer [512][Hp][Hp][C]
// ---------------------------------------------------------------------------
__global__ void zero_halo(u16* __restrict__ buf, int Hp, int C, int total8)
{
    int i = blockIdx.x * 256 + threadIdx.x;
    if (i >= total8) return;
    int c8 = i % (C / 8);
    int p  = i / (C / 8);
    int ring = 4 * Hp - 4;
    int h = p % ring;
    int b = p / ring;
    int y, x;
    if (h < Hp)              { y = 0;              x = h; }
    else if (h < 2 * Hp)     { y = Hp - 1;         x = h - Hp; }
    else if (h < 3 * Hp - 2) { y = h - 2 * Hp + 1; x = 0; }
    else                     { y = h - 3 * Hp + 3; x = Hp - 1; }
    uint4 z = make_uint4(0u, 0u, 0u, 0u);
    *(uint4*)(buf + ((size_t)((b * Hp + y) * Hp + x) * C) + c8 * 8) = z;
}

// ---------------------------------------------------------------------------
// Layer 0: direct conv 3->64, 32x32, output PADDED NHWC [512][34][34][64]
// ---------------------------------------------------------------------------
__global__ __launch_bounds__(256) void conv0_kernel(
    const float* __restrict__ x, const float* __restrict__ w,
    const float* __restrict__ bias, u16* __restrict__ out)
{
    __shared__ __align__(16) float xs[3][6][36];
    const int t  = threadIdx.x;
    const int b  = blockIdx.x >> 3;
    const int y0 = (blockIdx.x & 7) * 4;

    for (int i = t; i < 3 * 6 * 36; i += 256) {
        int ci  = i / 216;
        int rem = i % 216;
        int r   = rem / 36;
        int c   = rem % 36;
        int gy  = y0 - 1 + r;
        int gx  = c - 1;
        float v = 0.f;
        if ((unsigned)gy < 32u && (unsigned)gx < 32u)
            v = x[((b * 3 + ci) * 32 + gy) * 32 + gx];
        xs[ci][r][c] = v;
    }
    const int lane = t & 63;
    const int wv   = t >> 6;
    float wr[27];
    #pragma unroll
    for (int k = 0; k < 27; k++) wr[k] = w[lane * 27 + k];
    const float bz = bias[lane];
    __syncthreads();

    const int y = y0 + wv;
    u16* orow = out + ((size_t)((b * 34 + y + 1) * 34 + 1) * 64) + lane;
    for (int xg = 0; xg < 32; xg += 4) {
        float a0 = bz, a1 = bz, a2 = bz, a3 = bz;
        #pragma unroll
        for (int ci = 0; ci < 3; ci++) {
            #pragma unroll
            for (int rr = 0; rr < 3; rr++) {
                const float* row = &xs[ci][wv + rr][0];
                float4 c03 = *(const float4*)(row + xg);
                float2 c45 = *(const float2*)(row + xg + 4);
                float w0 = wr[ci * 9 + rr * 3 + 0];
                float w1 = wr[ci * 9 + rr * 3 + 1];
                float w2 = wr[ci * 9 + rr * 3 + 2];
                a0 += c03.x * w0 + c03.y * w1 + c03.z * w2;
                a1 += c03.y * w0 + c03.z * w1 + c03.w * w2;
                a2 += c03.z * w0 + c03.w * w1 + c45.x * w2;
                a3 += c03.w * w0 + c45.x * w1 + c45.y * w2;
            }
        }
        orow[(xg + 0) * 64] = f2bf(fmaxf(a0, 0.f));
        orow[(xg + 1) * 64] = f2bf(fmaxf(a1, 0.f));
        orow[(xg + 2) * 64] = f2bf(fmaxf(a2, 0.f));
        orow[(xg + 3) * 64] = f2bf(fmaxf(a3, 0.f));
    }
}

// ---------------------------------------------------------------------------
// Merged weight repack, LDS-staged so BOTH global sides are coalesced.
// ---------------------------------------------------------------------------
struct RepackArgs {
    const float* src[14];
    u16* dst[14];
    int p1[14];        // Cin (conv) or K (lin)
    int p2[14];        // 0 (conv) or N (lin)
    int startBlk[15];
    int nseg;
};

__global__ __launch_bounds__(256) void repack_all(RepackArgs a)
{
    __shared__ __align__(16) u16 lds[9216];
    int blk = blockIdx.x;
    int s = 0;
    #pragma unroll 1
    while (s + 1 < a.nseg && blk >= a.startBlk[s + 1]) s++;
    const int cb = blk - a.startBlk[s];
    const int t  = threadIdx.x;

    if (a.p2[s] == 0) {
        // ---- conv: block covers 9216 consecutive elements of src AND dst ----
        const int Cin = a.p1[s];
        const int logCin = __builtin_ctz(Cin);
        const float* src = a.src[s] + (size_t)cb * 9216;
        u16* dst = a.dst[s] + (size_t)cb * 9216;
        #pragma unroll
        for (int it = 0; it < 9; it++) {
            int j4 = it * 256 + t;                       // float4 index 0..2303
            float4 v = *(const float4*)(src + j4 * 4);
            ushort4 h;
            h.x = f2bf(v.x); h.y = f2bf(v.y); h.z = f2bf(v.z); h.w = f2bf(v.w);
            *(ushort4*)(lds + j4 * 4) = h;
        }
        __syncthreads();
        #pragma unroll
        for (int it = 0; it < 9; it++) {
            int o4   = (it * 256 + t) * 4;               // dst linear (co*9+sh)*Cin+ci
            int ci   = o4 & (Cin - 1);
            int rest = o4 >> logCin;                     // co*9 + sh
            int co   = rest / 9;
            int sh   = rest - co * 9;
            int sb   = (co << logCin) * 9 + ci * 9 + sh; // src-order LDS index
            ushort4 h;
            h.x = lds[sb]; h.y = lds[sb + 9]; h.z = lds[sb + 18]; h.w = lds[sb + 27];
            *(ushort4*)(dst + o4) = h;
        }
    } else {
        // ---- linear: 64x64 tile transpose f32[K][N] -> bf16[N][K] ----
        const int K = a.p1[s], N = a.p2[s];
        const int ntx = N >> 6;
        const int k0 = (cb / ntx) * 64, n0 = (cb % ntx) * 64;
        const float* src = a.src[s];
        u16* dst = a.dst[s];
        const int r = t >> 4, c4 = (t & 15) * 4;         // lds pitch 72 u16
        #pragma unroll
        for (int rr = 0; rr < 64; rr += 16) {
            float4 v = *(const float4*)(src + (size_t)(k0 + r + rr) * N + n0 + c4);
            u16* p = lds + (r + rr) * 72 + c4;
            p[0] = f2bf(v.x); p[1] = f2bf(v.y); p[2] = f2bf(v.z); p[3] = f2bf(v.w);
        }
        __syncthreads();
        #pragma unroll
        for (int it = 0; it < 2; it++) {
            int ov = it * 256 + t;                       // 0..511 output vec8s
            int n  = ov >> 3;
            int kq = (ov & 7) * 8;
            __align__(16) u16 h[8];
            #pragma unroll
            for (int j = 0; j < 8; j++) h[j] = lds[(kq + j) * 72 + n];
            *(uint4*)(dst + (size_t)(n0 + n) * K + k0 + kq) = *(uint4*)h;
        }
    }
}

// ---------------------------------------------------------------------------
// Conv shift-GEMM, bf16 MFMA 16x16x32.
// A-fragments are loaded DIRECTLY from global (NHWC makes the 16x32 fragment a
// dense, 16B-aligned per-lane load; input is L2/L3-hot across taps) — no A-LDS.
// Only B (weights) is LDS-staged, double-buffered, XOR-8 swizzle via source
// permutation. launch_bounds(256,2): VGPR cap 256 — (256,8) caused a 64-VGPR
// clamp and catastrophic scratch spill (1.3 GB HBM traffic per dispatch).
// BM=128: 4 waves 2x2 (wave cols = BN/2). BM=256: 4 waves 4x1 (wave cols = BN).
// ---------------------------------------------------------------------------
template <int BM, int BN>
__global__ __launch_bounds__(256, 2) void conv_gemm(
    const u16* __restrict__ in, const u16* __restrict__ wt,
    const float* __restrict__ bias, u16* __restrict__ out,
    float* __restrict__ partial, size_t pstride,
    int H, int Cin, int Cout, int logHW, int logW, int splitN,
    int outPad, int poolMode)
{
    constexpr int BK = 64;
    constexpr int WC = (BM == 256) ? BN : (BN / 2);   // wave cols
    constexpr int NT = WC / 16;
    constexpr int NB_B = BN / 32;
    constexpr int BSZ = BN * BK;
    __shared__ u16 Bs[2 * BSZ];

    const int Nblocks = Cout / BN;
    const int per = gridDim.x >> 3;
    const int bid = (blockIdx.x & 7) * per + (blockIdx.x >> 3);
    const int sp   = bid % splitN;
    const int tile = bid / splitN;
    const int m0 = (tile / Nblocks) * BM;
    const int n0 = (tile % Nblocks) * BN;

    const int t    = threadIdx.x;
    const int lane = t & 63;
    const int wave = t >> 6;
    const int quad = lane >> 4;
    const int l16  = lane & 15;
    const int wm   = (BM == 256) ? wave : (wave >> 1);
    const int wn   = (BM == 256) ? 0 : (wave & 1);
    const int W    = H;
    const int Wp   = H + 2;
    const int HW   = 1 << logHW;
    const int col8 = t & 7;
    const int r0   = t >> 3;
    const int scol = col8 ^ (r0 & 7);

    const int CinB = Cin * 2;

    // per-thread A fragment base (bytes): padded-pixel addr + quad channel chunk
    int aBase[4];
    #pragma unroll
    for (int mt = 0; mt < 4; mt++) {
        int m  = m0 + wm * 64 + mt * 16 + l16;
        int b  = m >> logHW;
        int rm = m & (HW - 1);
        int y  = rm >> logW;
        int xx = rm & (W - 1);
        aBase[mt] = ((b * Wp + y + 1) * Wp + xx + 1) * CinB + quad * 16;
    }
    int vB[NB_B];
    #pragma unroll
    for (int j = 0; j < NB_B; j++)
        vB[j] = (n0 + r0 + 32 * j) * 9 * CinB + scol * 16;

    const int logKB = (Cin == 64) ? 0 : (Cin == 128) ? 1 : (Cin == 256) ? 2 : 3;
    const int KB  = 1 << logKB;
    const int T   = 9 * KB;
    const int len = T / splitN;
    const int it0 = sp * len;

    int s0 = it0 >> logKB;
    int c3 = s0 - (s0 / 3) * 3;
    int ta = ((s0 / 3 - 1) * Wp + (c3 - 1)) * CinB;
    int kb = (it0 & (KB - 1)) * 128;
    int tb = it0 * 128;

    const char* const inB = (const char*)in;
    const char* const wtB = (const char*)wt;

    floatx4 acc[4][NT];
    #pragma unroll
    for (int i = 0; i < 4; i++)
        #pragma unroll
        for (int j = 0; j < NT; j++)
            acc[i][j] = (floatx4){0.f, 0.f, 0.f, 0.f};

    const int sw = (l16 & 7) * 8;

    auto stageB = [&](int tbv, int buf) {
        u16* lb = Bs + buf * BSZ + t * 8;
        #pragma unroll
        for (int j = 0; j < NB_B; j++)
            async_copy16(lb + j * 2048, (const u16*)(wtB + (tbv + vB[j])));
    };

    // prologue: stage B(0) into buf 0
    stageB(tb, 0);
    tb += 128;
    __syncthreads();                       // implicit vmcnt(0): buf0 ready

    int cur = 0;
    for (int it = 0; it < len; it++) {
        if (it + 1 < len) {                // prefetch next B tile
            stageB(tb, cur ^ 1);
            tb += 128;
        }
        const int offs = ta + kb;          // A byte offset for THIS iter
        kb += 128;
        if (kb == CinB) {
            kb = 0;
            ta += (c3 == 2) ? (Wp - 2) * CinB : CinB;
            c3 = (c3 == 2) ? 0 : c3 + 1;
        }

        // A fragments straight from global (L2/L3-hot)
        bf16x8 af[2][4];
        #pragma unroll
        for (int kk2 = 0; kk2 < 2; kk2++)
            #pragma unroll
            for (int mt = 0; mt < 4; mt++)
                af[kk2][mt] = *(const bf16x8*)(inB + (offs + aBase[mt] + kk2 * 64));

        const u16* Bb = Bs + cur * BSZ;
        #pragma unroll
        for (int kk2 = 0; kk2 < 2; kk2++) {
            int cbo = kk2 * 32 + quad * 8;
            bf16x8 bfv[NT];
            #pragma unroll
            for (int nt = 0; nt < NT; nt++)
                bfv[nt] = *(const bf16x8*)(Bb + (wn * WC + nt * 16 + l16) * 64 + (cbo ^ sw));
            #pragma unroll
            for (int mt = 0; mt < 4; mt++)
                #pragma unroll
                for (int nt = 0; nt < NT; nt++)
                    acc[mt][nt] = __builtin_amdgcn_mfma_f32_16x16x32_bf16(
                        af[kk2][mt], bfv[nt], acc[mt][nt], 0, 0, 0);
        }
        __syncthreads();                   // prefetch done + all reads of cur done
        cur ^= 1;
    }

    const int ngb = n0 + wn * WC + l16;

    if (splitN > 1) {
        float* pout = partial + (size_t)sp * pstride;
        #pragma unroll
        for (int mt = 0; mt < 4; mt++)
            #pragma unroll
            for (int r = 0; r < 4; r++) {
                int mg = m0 + wm * 64 + mt * 16 + quad * 4 + r;
                float* op = pout + (size_t)mg * Cout + ngb;
                #pragma unroll
                for (int nt = 0; nt < NT; nt++)
                    op[nt * 16] = acc[mt][nt][r];
            }
        return;
    }

    float bzv[NT];
    #pragma unroll
    for (int nt = 0; nt < NT; nt++) bzv[nt] = bias[ngb + nt * 16];

    if (poolMode) {
        const int Hpo = (H >> 1) + 2;
        if (logW == 5) {            // W=32: y-partner = mt+2, in-lane
            #pragma unroll
            for (int mt = 0; mt < 2; mt++)
                #pragma unroll
                for (int rp = 0; rp < 2; rp++) {
                    int m1 = m0 + wm * 64 + mt * 16 + quad * 4 + 2 * rp;
                    int b  = m1 >> logHW;
                    int rm = m1 & (HW - 1);
                    int yp = (rm >> logW) >> 1;
                    int xp = (rm & (W - 1)) >> 1;
                    u16* op = out + (size_t)((b * Hpo + yp + 1) * Hpo + xp + 1) * Cout + ngb;
                    #pragma unroll
                    for (int nt = 0; nt < NT; nt++) {
                        float v = fmaxf(
                            fmaxf(acc[mt][nt][2 * rp], acc[mt][nt][2 * rp + 1]),
                            fmaxf(acc[mt + 2][nt][2 * rp], acc[mt + 2][nt][2 * rp + 1]));
                        op[nt * 16] = f2bf(fmaxf(v + bzv[nt], 0.f));
                    }
                }
        } else if (logW == 4) {     // W=16: y-partner = mt+1, in-lane
            #pragma unroll
            for (int mtp = 0; mtp < 2; mtp++)
                #pragma unroll
                for (int rp = 0; rp < 2; rp++) {
                    int mt = 2 * mtp;
                    int m1 = m0 + wm * 64 + mt * 16 + quad * 4 + 2 * rp;
                    int b  = m1 >> logHW;
                    int rm = m1 & (HW - 1);
                    int yp = (rm >> logW) >> 1;
                    int xp = (rm & (W - 1)) >> 1;
                    u16* op = out + (size_t)((b * Hpo + yp + 1) * Hpo + xp + 1) * Cout + ngb;
                    #pragma unroll
                    for (int nt = 0; nt < NT; nt++) {
                        float v = fmaxf(
                            fmaxf(acc[mt][nt][2 * rp], acc[mt][nt][2 * rp + 1]),
                            fmaxf(acc[mt + 1][nt][2 * rp], acc[mt + 1][nt][2 * rp + 1]));
                        op[nt * 16] = f2bf(fmaxf(v + bzv[nt], 0.f));
                    }
                }
        } else {                    // W=8: y-partner = quad+2 via shfl32
            #pragma unroll
            for (int mt = 0; mt < 4; mt++)
                #pragma unroll
                for (int rp = 0; rp < 2; rp++) {
                    int m1 = m0 + wm * 64 + mt * 16 + quad * 4 + 2 * rp;
                    int b  = m1 >> logHW;
                    int rm = m1 & (HW - 1);
                    int yp = (rm >> logW) >> 1;
                    int xp = (rm & (W - 1)) >> 1;
                    u16* op = out + (size_t)((b * Hpo + yp + 1) * Hpo + xp + 1) * Cout + ngb;
                    #pragma unroll
                    for (int nt = 0; nt < NT; nt++) {
                        float a = fmaxf(acc[mt][nt][2 * rp], acc[mt][nt][2 * rp + 1]);
                        float p = __shfl_xor(a, 32, 64);
                        float v = fmaxf(a, p);
                        if (quad < 2)
                            op[nt * 16] = f2bf(fmaxf(v + bzv[nt], 0.f));
                    }
                }
        }
        return;
    }

    #pragma unroll
    for (int mt = 0; mt < 4; mt++) {
        #pragma unroll
        for (int r = 0; r < 4; r++) {
            int mg = m0 + wm * 64 + mt * 16 + quad * 4 + r;
            size_t obase;
            if (outPad) {
                int b  = mg >> logHW;
                int rm = mg & (HW - 1);
                int y  = rm >> logW;
                int xx = rm & (W - 1);
                obase = (size_t)((b * Wp + y + 1) * Wp + xx + 1) * Cout;
            } else {
                obase = (size_t)mg * Cout;
            }
            u16* op = out + obase + ngb;
            #pragma unroll
            for (int nt = 0; nt < NT; nt++)
                op[nt * 16] = f2bf(fmaxf(acc[mt][nt][r] + bzv[nt], 0.f));
        }
    }
}

// sum split partials + bias + relu -> bf16 NHWC (padded out optional)
__global__ void reduce_split(const float* __restrict__ partial,
                             const float* __restrict__ bias, u16* __restrict__ out,
                             int MN, int C, int logC, int splitN, size_t pstride,
                             int H, int logHW, int logW, int outPad)
{
    int i4 = (blockIdx.x * 256 + threadIdx.x) * 4;
    if (i4 >= MN) return;
    float4 s = *(const float4*)(partial + i4);
    for (int sp = 1; sp < splitN; sp++) {
        float4 p = *(const float4*)(partial + (size_t)sp * pstride + i4);
        s.x += p.x; s.y += p.y; s.z += p.z; s.w += p.w;
    }
    int n = i4 & (C - 1);
    int m = i4 >> logC;
    size_t obase;
    if (outPad) {
        int Wp = H + 2;
        int b  = m >> logHW;
        int rm = m & ((1 << logHW) - 1);
        int y  = rm >> logW;
        int xx = rm & (H - 1);
        obase = (size_t)((b * Wp + y + 1) * Wp + xx + 1) * C;
    } else {
        obase = (size_t)m * C;
    }
    ushort4 o;
    o.x = f2bf(fmaxf(s.x + bias[n + 0], 0.f));
    o.y = f2bf(fmaxf(s.y + bias[n + 1], 0.f));
    o.z = f2bf(fmaxf(s.z + bias[n + 2], 0.f));
    o.w = f2bf(fmaxf(s.w + bias[n + 3], 0.f));
    *(ushort4*)(out + obase + n) = o;
}

// sum split partials + bias + relu + 2x2 maxpool -> bf16 (padded optional)
__global__ void reduce_pool(const float* __restrict__ partial,
                            const float* __restrict__ bias, u16* __restrict__ out,
                            int total4, int C, int splitN, size_t pstride,
                            int H, int outPad)
{
    int idx = blockIdx.x * 256 + threadIdx.x;
    if (idx >= total4) return;
    int c4 = idx % (C / 4);
    int p  = idx / (C / 4);
    int Ho = H >> 1;
    int xp = p % Ho; p /= Ho;
    int yp = p % Ho;
    int b  = p / Ho;
    int n  = c4 * 4;
    float4 best;
    bool first = true;
    #pragma unroll
    for (int dy = 0; dy < 2; dy++)
        #pragma unroll
        for (int dx = 0; dx < 2; dx++) {
            int m = (b * H + 2 * yp + dy) * H + 2 * xp + dx;
            const float* q = partial + (size_t)m * C + n;
            float4 s = *(const float4*)q;
            for (int sp = 1; sp < splitN; sp++) {
                float4 pp = *(const float4*)(q + (size_t)sp * pstride);
                s.x += pp.x; s.y += pp.y; s.z += pp.z; s.w += pp.w;
            }
            if (first) { best = s; first = false; }
            else {
                best.x = fmaxf(best.x, s.x); best.y = fmaxf(best.y, s.y);
                best.z = fmaxf(best.z, s.z); best.w = fmaxf(best.w, s.w);
            }
        }
    size_t obase;
    if (outPad) {
        int Hpo = Ho + 2;
        obase = (size_t)((b * Hpo + yp + 1) * Hpo + xp + 1) * C;
    } else {
        obase = (size_t)((b * Ho + yp) * Ho + xp) * C;
    }
    ushort4 o;
    o.x = f2bf(fmaxf(best.x + bias[n + 0], 0.f));
    o.y = f2bf(fmaxf(best.y + bias[n + 1], 0.f));
    o.z = f2bf(fmaxf(best.z + bias[n + 2], 0.f));
    o.w = f2bf(fmaxf(best.w + bias[n + 3], 0.f));
    *(ushort4*)(out + obase + n) = o;
}

// ---------------------------------------------------------------------------
// Generic small GEMM: out[M,N] = act(A[M,K](bf16) @ Bt[N,K](bf16)^T + bias)
// ---------------------------------------------------------------------------
template <bool RELU, bool OUTBF>
__global__ __launch_bounds__(256) void gemm64(
    const u16* __restrict__ A, const u16* __restrict__ Bt,
    const float* __restrict__ bias, void* __restrict__ outv,
    int M, int N, int K)
{
    constexpr int LDP = 72;
    __shared__ u16 As[64 * LDP];
    __shared__ u16 Bs[64 * LDP];

    const int nb = N >> 6;
    const int m0 = (blockIdx.x / nb) * 64;
    const int n0 = (blockIdx.x % nb) * 64;
    const int t = threadIdx.x, lane = t & 63, wave = t >> 6;
    const int quad = lane >> 4, l16 = lane & 15;
    const int wm = wave >> 1, wn = wave & 1;
    const int col8 = t & 7, r0 = t >> 3;

    floatx4 acc[2][2];
    #pragma unroll
    for (int i = 0; i < 2; i++)
        #pragma unroll
        for (int j = 0; j < 2; j++)
            acc[i][j] = (floatx4){0.f, 0.f, 0.f, 0.f};

    for (int kb = 0; kb < K; kb += 64) {
        #pragma unroll
        for (int j = 0; j < 2; j++) {
            int row = r0 + 32 * j;
            *(uint4*)(As + row * LDP + col8 * 8) =
                *(const uint4*)(A + (size_t)(m0 + row) * K + kb + col8 * 8);
            *(uint4*)(Bs + row * LDP + col8 * 8) =
                *(const uint4*)(Bt + (size_t)(n0 + row) * K + kb + col8 * 8);
        }
        __syncthreads();
        #pragma unroll
        for (int kk = 0; kk < 64; kk += 32) {
            bf16x8 af[2], bfv[2];
            #pragma unroll
            for (int mt = 0; mt < 2; mt++)
                af[mt] = *(const bf16x8*)(As + (wm * 32 + mt * 16 + l16) * LDP + kk + quad * 8);
            #pragma unroll
            for (int nt = 0; nt < 2; nt++)
                bfv[nt] = *(const bf16x8*)(Bs + (wn * 32 + nt * 16 + l16) * LDP + kk + quad * 8);
            #pragma unroll
            for (int mt = 0; mt < 2; mt++)
                #pragma unroll
                for (int nt = 0; nt < 2; nt++)
                    acc[mt][nt] = __builtin_amdgcn_mfma_f32_16x16x32_bf16(
                        af[mt], bfv[nt], acc[mt][nt], 0, 0, 0);
        }
        __syncthreads();
    }
    #pragma unroll
    for (int mt = 0; mt < 2; mt++) {
        #pragma unroll
        for (int nt = 0; nt < 2; nt++) {
            #pragma unroll
            for (int r = 0; r < 4; r++) {
                int mg = m0 + wm * 32 + mt * 16 + quad * 4 + r;
                int ng = n0 + wn * 32 + nt * 16 + l16;
                float v = acc[mt][nt][r] + bias[ng];
                if (RELU) v = fmaxf(v, 0.f);
                if (OUTBF) ((u16*)outv)[(size_t)mg * N + ng] = f2bf(v);
                else       ((float*)outv)[(size_t)mg * N + ng] = v;
            }
        }
    }
}

// ---------------------------------------------------------------------------
__global__ __launch_bounds__(256) void graph_tile(
    const float* __restrict__ low, const int* __restrict__ target,
    float* __restrict__ gpre, float* __restrict__ ggt)
{
    __shared__ float Al[64 * 132];
    __shared__ float Bl[128 * 68];
    const int t = threadIdx.x;
    const int gr0 = (blockIdx.x >> 3) * 64;
    const int gc0 = (blockIdx.x & 7) * 64;

    #pragma unroll
    for (int j = 0; j < 32; j++) {
        int flat = t + 256 * j;
        int k = flat & 127;
        int rc = flat >> 7;
        Al[rc * 132 + k] = low[(size_t)(gr0 + rc) * 128 + k];
        Bl[k * 68 + rc]  = low[(size_t)(gc0 + rc) * 128 + k];
    }
    __syncthreads();

    const int tx = t & 15, ty = t >> 4;
    float acc[4][4];
    #pragma unroll
    for (int r = 0; r < 4; r++)
        #pragma unroll
        for (int c = 0; c < 4; c++) acc[r][c] = 0.f;

    for (int k = 0; k < 128; k++) {
        float a[4], b[4];
        #pragma unroll
        for (int r = 0; r < 4; r++) a[r] = Al[(ty * 4 + r) * 132 + k];
        #pragma unroll
        for (int c = 0; c < 4; c++) b[c] = Bl[k * 68 + tx * 4 + c];
        #pragma unroll
        for (int r = 0; r < 4; r++)
            #pragma unroll
            for (int c = 0; c < 4; c++) acc[r][c] += a[r] * b[c];
    }
    #pragma unroll
    for (int r = 0; r < 4; r++) {
        int row = gr0 + ty * 4 + r;
        int tr  = target[row];
        float4 gp, gg;
        float* pp = (float*)&gp;
        float* gg_ = (float*)&gg;
        #pragma unroll
        for (int c = 0; c < 4; c++) {
            pp[c]  = 1.f / (1.f + __expf(-acc[r][c]));
            gg_[c] = (tr == target[gc0 + tx * 4 + c]) ? 1.f : 0.f;
        }
        *(float4*)(gpre + (size_t)row * 512 + gc0 + tx * 4) = gp;
        *(float4*)(ggt  + (size_t)row * 512 + gc0 + tx * 4) = gg;
    }
}

// ---------------------------------------------------------------------------
__global__ __launch_bounds__(256) void cls_kernel(
    const u16* __restrict__ feat, const float* __restrict__ w,
    const float* __restrict__ bias, float* __restrict__ out)
{
    __shared__ float ws[5120];
    const int t = threadIdx.x;
    for (int i = t; i < 5120; i += 256) ws[i] = w[i];
    __syncthreads();
    const int lane = t & 63;
    const int row  = blockIdx.x * 4 + (t >> 6);
    float a[10];
    #pragma unroll
    for (int j = 0; j < 10; j++) a[j] = 0.f;
    #pragma unroll
    for (int i = 0; i < 8; i++) {
        int k = i * 64 + lane;
        float f = bf2f(feat[(size_t)row * 512 + k]);
        #pragma unroll
        for (int j = 0; j < 10; j++) a[j] += f * ws[k * 10 + j];
    }
    #pragma unroll
    for (int j = 0; j < 10; j++)
        #pragma unroll
        for (int off = 32; off > 0; off >>= 1)
            a[j] += __shfl_down(a[j], off, 64);
    if (lane == 0) {
        #pragma unroll
        for (int j = 0; j < 10; j++) out[row * 10 + j] = a[j] + bias[j];
    }
}

// ---------------------------------------------------------------------------
extern "C" void kernel_launch(void* const* d_in, const int* in_sizes, int n_in,
                              void* d_out, int out_size, void* d_ws, size_t ws_size,
                              hipStream_t stream)
{
    const float* x      = (const float*)d_in[0];
    const int*   target = (const int*)d_in[1];
    const float* conv_w[13];
    const float* conv_b[13];
    for (int i = 0; i < 13; i++) {
        conv_w[i] = (const float*)d_in[2 + 2 * i];
        conv_b[i] = (const float*)d_in[3 + 2 * i];
    }
    const float* lin1_w = (const float*)d_in[28];
    const float* lin1_b = (const float*)d_in[29];
    const float* lin2_w = (const float*)d_in[30];
    const float* lin2_b = (const float*)d_in[31];
    const float* cls_w  = (const float*)d_in[32];
    const float* cls_b  = (const float*)d_in[33];
    float* out = (float*)d_out;

    static const int cin_arr[13]  = {3, 64, 64, 128, 128, 256, 256, 256, 512, 512, 512, 512, 512};
    static const int cout_arr[13] = {64, 64, 128, 128, 256, 256, 256, 512, 512, 512, 512, 512, 512};

    char* ws = (char*)d_ws;
    size_t off = 0;
    const size_t R0SZ = (size_t)512 * 34 * 34 * 64 * 2;
    const size_t R1SZ = (size_t)512 * 34 * 34 * 64 * 2;
    char* R0raw = ws + off; off += R0SZ;
    char* R1raw = ws + off; off += R1SZ;
    u16* R0 = (u16*)R0raw;
    u16* R1 = (u16*)R1raw;
    float* PA = (float*)(R0raw + 20971520);
    float* PB = (float*)(R1raw + 20971520);
    u16* wt[13];
    for (int i = 1; i < 13; i++) {
        wt[i] = (u16*)(ws + off);
        off += (size_t)cout_arr[i] * 9 * cin_arr[i] * 2;
    }
    u16* wtl1 = (u16*)(ws + off); off += (size_t)256 * 512 * 2;
    u16* wtl2 = (u16*)(ws + off); off += (size_t)128 * 256 * 2;
    u16* hbuf = (u16*)(ws + off); off += (size_t)512 * 256 * 2;
    float* lowbuf = (float*)(ws + off); off += (size_t)512 * 128 * 4;

    // ---- single merged repack launch (12 conv + 2 lin), LDS-staged ----
    RepackArgs ra;
    int nb = 0, blk = 0;
    ra.startBlk[0] = 0;
    for (int i = 1; i < 13; i++) {
        ra.src[nb] = conv_w[i];
        ra.dst[nb] = wt[i];
        ra.p1[nb] = cin_arr[i];
        ra.p2[nb] = 0;
        blk += cout_arr[i] * cin_arr[i] / 1024;   // 9216 elems per block
        nb++; ra.startBlk[nb] = blk;
    }
    ra.src[nb] = lin1_w; ra.dst[nb] = wtl1; ra.p1[nb] = 512; ra.p2[nb] = 256;
    blk += (512 / 64) * (256 / 64);
    nb++; ra.startBlk[nb] = blk;
    ra.src[nb] = lin2_w; ra.dst[nb] = wtl2; ra.p1[nb] = 256; ra.p2[nb] = 128;
    blk += (256 / 64) * (128 / 64);
    nb++; ra.startBlk[nb] = blk;
    ra.nseg = nb;
    repack_all<<<blk, 256, 0, stream>>>(ra);

    auto zh = [&](u16* buf, int Hp, int C) {
        int total8 = 512 * (4 * Hp - 4) * (C / 8);
        zero_halo<<<(total8 + 255) / 256, 256, 0, stream>>>(buf, Hp, C, total8);
    };
    auto launch_conv = [&](int li, int Hl, int bm, int bn, u16* inb, u16* outb,
                           float* part, int splitN, int outPad, int poolMode) {
        int Cin = cin_arr[li], Cout = cout_arr[li];
        int M = 512 * Hl * Hl;
        int logW = __builtin_ctz(Hl);
        int logHW = 2 * logW;
        size_t pstride = (size_t)M * Cout;
        int grid = (M / bm) * (Cout / bn) * splitN;
        if (bm == 256) {
            conv_gemm<256, 64><<<grid, 256, 0, stream>>>(
                inb, wt[li], conv_b[li], outb, part, pstride,
                Hl, Cin, Cout, logHW, logW, splitN, outPad, poolMode);
        } else if (bn == 128) {
            conv_gemm<128, 128><<<grid, 256, 0, stream>>>(
                inb, wt[li], conv_b[li], outb, part, pstride,
                Hl, Cin, Cout, logHW, logW, splitN, outPad, poolMode);
        } else {
            conv_gemm<128, 64><<<grid, 256, 0, stream>>>(
                inb, wt[li], conv_b[li], outb, part, pstride,
                Hl, Cin, Cout, logHW, logW, splitN, outPad, poolMode);
        }
    };
    auto launch_reduce = [&](int li, int Hl, u16* outb, float* part, int splitN, int outPad) {
        int Cout = cout_arr[li];
        int M = 512 * Hl * Hl;
        int logW = __builtin_ctz(Hl);
        size_t pstride = (size_t)M * Cout;
        int MN = M * Cout;
        reduce_split<<<(MN / 4 + 255) / 256, 256, 0, stream>>>(
            part, conv_b[li], outb, MN, Cout, __builtin_ctz(Cout),
            splitN, pstride, Hl, 2 * logW, logW, outPad);
    };
    auto launch_reduce_pool = [&](int li, int Hl, u16* outb, float* part, int splitN, int outPad) {
        int Cout = cout_arr[li];
        int M = 512 * Hl * Hl;
        size_t pstride = (size_t)M * Cout;
        int total4 = 512 * (Hl / 2) * (Hl / 2) * Cout / 4;
        reduce_pool<<<(total4 + 255) / 256, 256, 0, stream>>>(
            part, conv_b[li], outb, total4, Cout, splitN, pstride, Hl, outPad);
    };

    zh(R0, 34, 64);
    conv0_kernel<<<512 * 8, 256, 0, stream>>>(x, conv_w[0], conv_b[0], R0);

    zh(R1, 18, 64);
    launch_conv(1, 32, 256, 64, R0, R1, nullptr, 1, 0, 1);   // L1 + pool (BM=256)
    zh(R0, 18, 128);
    launch_conv(2, 16, 128, 128, R1, R0, nullptr, 1, 1, 0);  // L2
    zh(R1, 10, 128);
    launch_conv(3, 16, 128, 128, R0, R1, nullptr, 1, 0, 1);  // L3 + pool
    zh(R0, 10, 256);
    launch_conv(4, 8, 128, 128, R1, R0, nullptr, 1, 1, 0);   // L4
    zh(R1, 10, 256);
    launch_conv(5, 8, 128, 128, R0, R1, nullptr, 1, 1, 0);   // L5
    zh(R0, 6, 256);
    launch_conv(6, 8, 128, 128, R1, R0, nullptr, 1, 0, 1);   // L6 + pool
    zh(R1, 6, 512);
    launch_conv(7, 4, 128, 128, R0, R1, PB, 2, 1, 0);        // L7 split2
    launch_reduce(7, 4, R1, PB, 2, 1);
    zh(R0, 6, 512);
    launch_conv(8, 4, 128, 128, R1, R0, PA, 2, 1, 0);        // L8 split2
    launch_reduce(8, 4, R0, PA, 2, 1);
    zh(R1, 4, 512);
    launch_conv(9, 4, 128, 128, R0, R1, PB, 2, 0, 0);        // L9 split2
    launch_reduce_pool(9, 4, R1, PB, 2, 1);
    zh(R0, 4, 512);
    launch_conv(10, 2, 128, 64, R1, R0, PA, 4, 1, 0);        // L10 split4
    launch_reduce(10, 2, R0, PA, 4, 1);
    zh(R1, 4, 512);
    launch_conv(11, 2, 128, 64, R0, R1, PB, 4, 1, 0);        // L11 split4
    launch_reduce(11, 2, R1, PB, 4, 1);
    launch_conv(12, 2, 128, 64, R1, R0, PA, 4, 0, 0);        // L12 split4
    launch_reduce_pool(12, 2, R0, PA, 4, 0);                 // feat = R0 [512,512]

    u16* feat = R0;
    gemm64<true, true><<<(512 / 64) * (256 / 64), 256, 0, stream>>>(
        feat, wtl1, lin1_b, hbuf, 512, 256, 512);
    gemm64<false, false><<<(512 / 64) * (128 / 64), 256, 0, stream>>>(
        hbuf, wtl2, lin2_b, lowbuf, 512, 128, 256);
    graph_tile<<<64, 256, 0, stream>>>(lowbuf, target, out + 5120, out + 5120 + 262144);
    cls_kernel<<<128, 256, 0, stream>>>(feat, cls_w, cls_b, out);
}

// Round 5
// 683.135 us; speedup vs baseline: 2.3264x; 1.5308x over previous
//
#include <hip/hip_runtime.h>

typedef unsigned short u16;
typedef __bf16 bf16x8 __attribute__((ext_vector_type(8)));
typedef float floatx4 __attribute__((ext_vector_type(4)));

__device__ inline u16 f2bf(float f) {
    return __builtin_bit_cast(u16, (__bf16)f);   // v_cvt RNE, 1 op
}
__device__ inline float bf2f(u16 h) {
    return __uint_as_float(((unsigned int)h) << 16);
}

// async global->LDS, 16B per lane. LDS dest must be wave-uniform base + lane*16.
__device__ __forceinline__ void async_copy16(u16* lds, const u16* g) {
    __builtin_amdgcn_global_load_lds(
        (const __attribute__((address_space(1))) unsigned int*)(uintptr_t)g,
        (__attribute__((address_space(3))) unsigned int*)(unsigned int)(uintptr_t)lds,
        16, 0, 0);
}

// ---------------------------------------------------------------------------
// zero ONLY the 1-px halo ring of a padded NHWC buffer [512][Hp][Hp][C]
// ---------------------------------------------------------------------------
__global__ void zero_halo(u16* __restrict__ buf, int Hp, int C, int total8)
{
    int i = blockIdx.x * 256 + threadIdx.x;
    if (i >= total8) return;
    int c8 = i % (C / 8);
    int p  = i / (C / 8);
    int ring = 4 * Hp - 4;
    int h = p % ring;
    int b = p / ring;
    int y, x;
    if (h < Hp)              { y = 0;              x = h; }
    else if (h < 2 * Hp)     { y = Hp - 1;         x = h - Hp; }
    else if (h < 3 * Hp - 2) { y = h - 2 * Hp + 1; x = 0; }
    else                     { y = h - 3 * Hp + 3; x = Hp - 1; }
    uint4 z = make_uint4(0u, 0u, 0u, 0u);
    *(uint4*)(buf + ((size_t)((b * Hp + y) * Hp + x) * C) + c8 * 8) = z;
}

// ---------------------------------------------------------------------------
// Layer 0: direct conv 3->64, 32x32, output PADDED NHWC [512][34][34][64]
// ---------------------------------------------------------------------------
__global__ __launch_bounds__(256) void conv0_kernel(
    const float* __restrict__ x, const float* __restrict__ w,
    const float* __restrict__ bias, u16* __restrict__ out)
{
    __shared__ __align__(16) float xs[3][6][36];
    const int t  = threadIdx.x;
    const int b  = blockIdx.x >> 3;
    const int y0 = (blockIdx.x & 7) * 4;

    for (int i = t; i < 3 * 6 * 36; i += 256) {
        int ci  = i / 216;
        int rem = i % 216;
        int r   = rem / 36;
        int c   = rem % 36;
        int gy  = y0 - 1 + r;
        int gx  = c - 1;
        float v = 0.f;
        if ((unsigned)gy < 32u && (unsigned)gx < 32u)
            v = x[((b * 3 + ci) * 32 + gy) * 32 + gx];
        xs[ci][r][c] = v;
    }
    const int lane = t & 63;
    const int wv   = t >> 6;
    float wr[27];
    #pragma unroll
    for (int k = 0; k < 27; k++) wr[k] = w[lane * 27 + k];
    const float bz = bias[lane];
    __syncthreads();

    const int y = y0 + wv;
    u16* orow = out + ((size_t)((b * 34 + y + 1) * 34 + 1) * 64) + lane;
    for (int xg = 0; xg < 32; xg += 4) {
        float a0 = bz, a1 = bz, a2 = bz, a3 = bz;
        #pragma unroll
        for (int ci = 0; ci < 3; ci++) {
            #pragma unroll
            for (int rr = 0; rr < 3; rr++) {
                const float* row = &xs[ci][wv + rr][0];
                float4 c03 = *(const float4*)(row + xg);
                float2 c45 = *(const float2*)(row + xg + 4);
                float w0 = wr[ci * 9 + rr * 3 + 0];
                float w1 = wr[ci * 9 + rr * 3 + 1];
                float w2 = wr[ci * 9 + rr * 3 + 2];
                a0 += c03.x * w0 + c03.y * w1 + c03.z * w2;
                a1 += c03.y * w0 + c03.z * w1 + c03.w * w2;
                a2 += c03.z * w0 + c03.w * w1 + c45.x * w2;
                a3 += c03.w * w0 + c45.x * w1 + c45.y * w2;
            }
        }
        orow[(xg + 0) * 64] = f2bf(fmaxf(a0, 0.f));
        orow[(xg + 1) * 64] = f2bf(fmaxf(a1, 0.f));
        orow[(xg + 2) * 64] = f2bf(fmaxf(a2, 0.f));
        orow[(xg + 3) * 64] = f2bf(fmaxf(a3, 0.f));
    }
}

// ---------------------------------------------------------------------------
// Merged weight repack, LDS-staged so BOTH global sides are coalesced.
// ---------------------------------------------------------------------------
struct RepackArgs {
    const float* src[14];
    u16* dst[14];
    int p1[14];        // Cin (conv) or K (lin)
    int p2[14];        // 0 (conv) or N (lin)
    int startBlk[15];
    int nseg;
};

__global__ __launch_bounds__(256) void repack_all(RepackArgs a)
{
    __shared__ __align__(16) u16 lds[9216];
    int blk = blockIdx.x;
    int s = 0;
    #pragma unroll 1
    while (s + 1 < a.nseg && blk >= a.startBlk[s + 1]) s++;
    const int cb = blk - a.startBlk[s];
    const int t  = threadIdx.x;

    if (a.p2[s] == 0) {
        // ---- conv: block covers 9216 consecutive elements of src AND dst ----
        const int Cin = a.p1[s];
        const int logCin = __builtin_ctz(Cin);
        const float* src = a.src[s] + (size_t)cb * 9216;
        u16* dst = a.dst[s] + (size_t)cb * 9216;
        #pragma unroll
        for (int it = 0; it < 9; it++) {
            int j4 = it * 256 + t;                       // float4 index 0..2303
            float4 v = *(const float4*)(src + j4 * 4);
            ushort4 h;
            h.x = f2bf(v.x); h.y = f2bf(v.y); h.z = f2bf(v.z); h.w = f2bf(v.w);
            *(ushort4*)(lds + j4 * 4) = h;
        }
        __syncthreads();
        #pragma unroll
        for (int it = 0; it < 9; it++) {
            int o4   = (it * 256 + t) * 4;               // dst linear (co*9+sh)*Cin+ci
            int ci   = o4 & (Cin - 1);
            int rest = o4 >> logCin;                     // co*9 + sh
            int co   = rest / 9;
            int sh   = rest - co * 9;
            int sb   = (co << logCin) * 9 + ci * 9 + sh; // src-order LDS index
            ushort4 h;
            h.x = lds[sb]; h.y = lds[sb + 9]; h.z = lds[sb + 18]; h.w = lds[sb + 27];
            *(ushort4*)(dst + o4) = h;
        }
    } else {
        // ---- linear: 64x64 tile transpose f32[K][N] -> bf16[N][K] ----
        const int K = a.p1[s], N = a.p2[s];
        const int ntx = N >> 6;
        const int k0 = (cb / ntx) * 64, n0 = (cb % ntx) * 64;
        const float* src = a.src[s];
        u16* dst = a.dst[s];
        const int r = t >> 4, c4 = (t & 15) * 4;         // lds pitch 72 u16
        #pragma unroll
        for (int rr = 0; rr < 64; rr += 16) {
            float4 v = *(const float4*)(src + (size_t)(k0 + r + rr) * N + n0 + c4);
            u16* p = lds + (r + rr) * 72 + c4;
            p[0] = f2bf(v.x); p[1] = f2bf(v.y); p[2] = f2bf(v.z); p[3] = f2bf(v.w);
        }
        __syncthreads();
        #pragma unroll
        for (int it = 0; it < 2; it++) {
            int ov = it * 256 + t;                       // 0..511 output vec8s
            int n  = ov >> 3;
            int kq = (ov & 7) * 8;
            __align__(16) u16 h[8];
            #pragma unroll
            for (int j = 0; j < 8; j++) h[j] = lds[(kq + j) * 72 + n];
            *(uint4*)(dst + (size_t)(n0 + n) * K + k0 + kq) = *(uint4*)h;
        }
    }
}

// ---------------------------------------------------------------------------
// Conv shift-GEMM (deep layers), bf16 MFMA 16x16x32. Double-buffered LDS for
// A and B; STAGE(t+1) before compute(t); one __syncthreads per K-step.
// BM=128: 4 waves 2x2 (wave cols = BN/2). BM=256: 4 waves 4x1 (wave cols = BN).
// ---------------------------------------------------------------------------
template <int BM, int BN>
__global__ __launch_bounds__(256) void conv_gemm(
    const u16* __restrict__ in, const u16* __restrict__ wt,
    const float* __restrict__ bias, u16* __restrict__ out,
    float* __restrict__ partial, size_t pstride,
    int H, int Cin, int Cout, int logHW, int logW, int splitN,
    int outPad, int poolMode)
{
    constexpr int BK = 64;
    constexpr int WC = (BM == 256) ? BN : (BN / 2);   // wave cols
    constexpr int NT = WC / 16;
    constexpr int NB_A = BM / 32;
    constexpr int NB_B = BN / 32;
    constexpr int ASZ = BM * BK;
    constexpr int BSZ = BN * BK;
    __shared__ u16 As[2 * ASZ];
    __shared__ u16 Bs[2 * BSZ];

    const int Nblocks = Cout / BN;
    const int per = gridDim.x >> 3;
    const int bid = (blockIdx.x & 7) * per + (blockIdx.x >> 3);
    const int sp   = bid % splitN;
    const int tile = bid / splitN;
    const int m0 = (tile / Nblocks) * BM;
    const int n0 = (tile % Nblocks) * BN;

    const int t    = threadIdx.x;
    const int lane = t & 63;
    const int wave = t >> 6;
    const int quad = lane >> 4;
    const int l16  = lane & 15;
    const int wm   = (BM == 256) ? wave : (wave >> 1);
    const int wn   = (BM == 256) ? 0 : (wave & 1);
    const int W    = H;
    const int Wp   = H + 2;
    const int HW   = 1 << logHW;
    const int col8 = t & 7;
    const int r0   = t >> 3;
    const int scol = col8 ^ (r0 & 7);

    const int CinB = Cin * 2;

    int vA[NB_A];
    #pragma unroll
    for (int j = 0; j < NB_A; j++) {
        int m  = m0 + r0 + 32 * j;
        int b  = m >> logHW;
        int rm = m & (HW - 1);
        int y  = rm >> logW;
        int xx = rm & (W - 1);
        vA[j] = ((b * Wp + y + 1) * Wp + xx + 1) * CinB + scol * 16;
    }
    int vB[NB_B];
    #pragma unroll
    for (int j = 0; j < NB_B; j++)
        vB[j] = (n0 + r0 + 32 * j) * 9 * CinB + scol * 16;

    const int logKB = (Cin == 64) ? 0 : (Cin == 128) ? 1 : (Cin == 256) ? 2 : 3;
    const int KB  = 1 << logKB;
    const int T   = 9 * KB;
    const int len = T / splitN;
    const int it0 = sp * len;

    int s0 = it0 >> logKB;
    int c3 = s0 - (s0 / 3) * 3;
    int ta = ((s0 / 3 - 1) * Wp + (c3 - 1)) * CinB;
    int kb = (it0 & (KB - 1)) * 128;
    int tb = it0 * 128;

    const char* const inB = (const char*)in;
    const char* const wtB = (const char*)wt;

    floatx4 acc[4][NT];
    #pragma unroll
    for (int i = 0; i < 4; i++)
        #pragma unroll
        for (int j = 0; j < NT; j++)
            acc[i][j] = (floatx4){0.f, 0.f, 0.f, 0.f};

    const int sw = (l16 & 7) * 8;

    // stage iteration's tiles into buffer half `buf`
    auto stage = [&](int ua, int tbv, int buf) {
        u16* la = As + buf * ASZ + t * 8;
        u16* lb = Bs + buf * BSZ + t * 8;
        #pragma unroll
        for (int j = 0; j < NB_A; j++)
            async_copy16(la + j * 2048, (const u16*)(inB + (ua + vA[j])));
        #pragma unroll
        for (int j = 0; j < NB_B; j++)
            async_copy16(lb + j * 2048, (const u16*)(wtB + (tbv + vB[j])));
    };
    auto advance = [&]() {
        tb += 128;
        kb += 128;
        if (kb == CinB) {
            kb = 0;
            ta += (c3 == 2) ? (Wp - 2) * CinB : CinB;
            c3 = (c3 == 2) ? 0 : c3 + 1;
        }
    };

    // prologue: stage iter 0 into buf 0
    stage(ta + kb, tb, 0);
    advance();
    __syncthreads();                       // implicit vmcnt(0): buf0 ready

    int cur = 0;
    for (int it = 0; it < len; it++) {
        if (it + 1 < len) {                // prefetch next tile into other half
            stage(ta + kb, tb, cur ^ 1);
            advance();
        }
        const u16* Ab = As + cur * ASZ;
        const u16* Bb = Bs + cur * BSZ;
        #pragma unroll
        for (int kk = 0; kk < BK; kk += 32) {
            bf16x8 af[4], bfv[NT];
            int cbo = kk + quad * 8;
            #pragma unroll
            for (int mt = 0; mt < 4; mt++)
                af[mt] = *(const bf16x8*)(Ab + (wm * 64 + mt * 16 + l16) * 64 + (cbo ^ sw));
            #pragma unroll
            for (int nt = 0; nt < NT; nt++)
                bfv[nt] = *(const bf16x8*)(Bb + (wn * WC + nt * 16 + l16) * 64 + (cbo ^ sw));
            #pragma unroll
            for (int mt = 0; mt < 4; mt++)
                #pragma unroll
                for (int nt = 0; nt < NT; nt++)
                    acc[mt][nt] = __builtin_amdgcn_mfma_f32_16x16x32_bf16(
                        af[mt], bfv[nt], acc[mt][nt], 0, 0, 0);
        }
        __syncthreads();                   // drains vmcnt (prefetch) + lgkmcnt
        cur ^= 1;
    }

    const int ngb = n0 + wn * WC + l16;

    if (splitN > 1) {
        float* pout = partial + (size_t)sp * pstride;
        #pragma unroll
        for (int mt = 0; mt < 4; mt++)
            #pragma unroll
            for (int r = 0; r < 4; r++) {
                int mg = m0 + wm * 64 + mt * 16 + quad * 4 + r;
                float* op = pout + (size_t)mg * Cout + ngb;
                #pragma unroll
                for (int nt = 0; nt < NT; nt++)
                    op[nt * 16] = acc[mt][nt][r];
            }
        return;
    }

    float bzv[NT];
    #pragma unroll
    for (int nt = 0; nt < NT; nt++) bzv[nt] = bias[ngb + nt * 16];

    if (poolMode) {
        const int Hpo = (H >> 1) + 2;
        if (logW == 5) {            // W=32: y-partner = mt+2, in-lane
            #pragma unroll
            for (int mt = 0; mt < 2; mt++)
                #pragma unroll
                for (int rp = 0; rp < 2; rp++) {
                    int m1 = m0 + wm * 64 + mt * 16 + quad * 4 + 2 * rp;
                    int b  = m1 >> logHW;
                    int rm = m1 & (HW - 1);
                    int yp = (rm >> logW) >> 1;
                    int xp = (rm & (W - 1)) >> 1;
                    u16* op = out + (size_t)((b * Hpo + yp + 1) * Hpo + xp + 1) * Cout + ngb;
                    #pragma unroll
                    for (int nt = 0; nt < NT; nt++) {
                        float v = fmaxf(
                            fmaxf(acc[mt][nt][2 * rp], acc[mt][nt][2 * rp + 1]),
                            fmaxf(acc[mt + 2][nt][2 * rp], acc[mt + 2][nt][2 * rp + 1]));
                        op[nt * 16] = f2bf(fmaxf(v + bzv[nt], 0.f));
                    }
                }
        } else if (logW == 4) {     // W=16: y-partner = mt+1, in-lane
            #pragma unroll
            for (int mtp = 0; mtp < 2; mtp++)
                #pragma unroll
                for (int rp = 0; rp < 2; rp++) {
                    int mt = 2 * mtp;
                    int m1 = m0 + wm * 64 + mt * 16 + quad * 4 + 2 * rp;
                    int b  = m1 >> logHW;
                    int rm = m1 & (HW - 1);
                    int yp = (rm >> logW) >> 1;
                    int xp = (rm & (W - 1)) >> 1;
                    u16* op = out + (size_t)((b * Hpo + yp + 1) * Hpo + xp + 1) * Cout + ngb;
                    #pragma unroll
                    for (int nt = 0; nt < NT; nt++) {
                        float v = fmaxf(
                            fmaxf(acc[mt][nt][2 * rp], acc[mt][nt][2 * rp + 1]),
                            fmaxf(acc[mt + 1][nt][2 * rp], acc[mt + 1][nt][2 * rp + 1]));
                        op[nt * 16] = f2bf(fmaxf(v + bzv[nt], 0.f));
                    }
                }
        } else {                    // W=8: y-partner = quad+2 via shfl32
            #pragma unroll
            for (int mt = 0; mt < 4; mt++)
                #pragma unroll
                for (int rp = 0; rp < 2; rp++) {
                    int m1 = m0 + wm * 64 + mt * 16 + quad * 4 + 2 * rp;
                    int b  = m1 >> logHW;
                    int rm = m1 & (HW - 1);
                    int yp = (rm >> logW) >> 1;
                    int xp = (rm & (W - 1)) >> 1;
                    u16* op = out + (size_t)((b * Hpo + yp + 1) * Hpo + xp + 1) * Cout + ngb;
                    #pragma unroll
                    for (int nt = 0; nt < NT; nt++) {
                        float a = fmaxf(acc[mt][nt][2 * rp], acc[mt][nt][2 * rp + 1]);
                        float p = __shfl_xor(a, 32, 64);
                        float v = fmaxf(a, p);
                        if (quad < 2)
                            op[nt * 16] = f2bf(fmaxf(v + bzv[nt], 0.f));
                    }
                }
        }
        return;
    }

    #pragma unroll
    for (int mt = 0; mt < 4; mt++) {
        #pragma unroll
        for (int r = 0; r < 4; r++) {
            int mg = m0 + wm * 64 + mt * 16 + quad * 4 + r;
            size_t obase;
            if (outPad) {
                int b  = mg >> logHW;
                int rm = mg & (HW - 1);
                int y  = rm >> logW;
                int xx = rm & (W - 1);
                obase = (size_t)((b * Wp + y + 1) * Wp + xx + 1) * Cout;
            } else {
                obase = (size_t)mg * Cout;
            }
            u16* op = out + obase + ngb;
            #pragma unroll
            for (int nt = 0; nt < NT; nt++)
                op[nt * 16] = f2bf(fmaxf(acc[mt][nt][r] + bzv[nt], 0.f));
        }
    }
}

// ---------------------------------------------------------------------------
// Halo-staged conv GEMM for early layers (row-aligned tiles within one image).
// The (R+2)x(W+2)xCin input halo is ONE contiguous global range; staged ONCE
// per block (XOR-8 chunk swizzle via source permutation). K-loop stages only
// the small B tile (double-buffered). Cuts A-staging traffic ~6x vs re-staging
// per tap and makes the per-iter barrier wait tiny.
// ---------------------------------------------------------------------------
template <int BM, int BN, int W, int CIN>
__global__ __launch_bounds__(256) void conv_halo(
    const u16* __restrict__ in, const u16* __restrict__ wt,
    const float* __restrict__ bias, u16* __restrict__ out,
    int outPad, int poolMode)
{
    constexpr int BK = 64;
    constexpr int WC = (BM == 256) ? BN : (BN / 2);
    constexpr int NT = WC / 16;
    constexpr int NB_B = BN / 32;
    constexpr int BSZ = BN * BK;
    constexpr int Wp = W + 2;
    constexpr int R  = BM / W;                 // rows per tile (8)
    constexpr int P  = (R + 2) * Wp;           // halo pixels
    constexpr int CinB = CIN * 2;              // bytes per pixel
    constexpr int CH = CinB / 16;              // 16B chunks per pixel (>=8)
    constexpr int LOG_CH = (CH == 8) ? 3 : 4;
    constexpr int HALO_CHUNKS = P * CH;
    constexpr int ROUNDS = (HALO_CHUNKS + 255) / 256;
    constexpr int logW = (W == 32) ? 5 : 4;
    constexpr int logHW = 2 * logW;
    constexpr int HW = 1 << logHW;
    constexpr int KB = CIN / 64;
    constexpr int T  = 9 * KB;

    __shared__ __align__(16) u16 Ah[P * CH * 8];   // halo (u16 units)
    __shared__ __align__(16) u16 Bs[2 * BSZ];

    constexpr int Nblocks = 1;                  // Cout == BN for all uses
    static_assert(true, "");
    const int per = gridDim.x >> 3;
    const int bid = (blockIdx.x & 7) * per + (blockIdx.x >> 3);
    const int m0 = (bid / Nblocks) * BM;
    const int n0 = (bid % Nblocks) * BN;

    const int t    = threadIdx.x;
    const int lane = t & 63;
    const int wave = t >> 6;
    const int quad = lane >> 4;
    const int l16  = lane & 15;
    const int wm   = (BM == 256) ? wave : (wave >> 1);
    const int wn   = (BM == 256) ? 0 : (wave & 1);
    const int col8 = t & 7;
    const int r0   = t >> 3;
    const int scol = col8 ^ (r0 & 7);

    const int b  = m0 >> logHW;
    const int y0 = (m0 & (HW - 1)) >> logW;

    // ---- stage halo (contiguous global range, swizzled source) ----
    const char* hsrc = (const char*)in + (size_t)((b * Wp + y0) * Wp) * CinB;
    #pragma unroll
    for (int rd = 0; rd < ROUNDS; rd++) {
        int i = rd * 256 + t;
        if ((HALO_CHUNKS % 256 == 0) || i < HALO_CHUNKS) {
            int pp   = i >> LOG_CH;
            int si   = i ^ (pp & 7);               // XOR low 3 chunk bits
            async_copy16(Ah + i * 8, (const u16*)(hsrc + (size_t)si * 16));
        }
    }

    // ---- B staging setup (identical to conv_gemm) ----
    int vB[NB_B];
    #pragma unroll
    for (int j = 0; j < NB_B; j++)
        vB[j] = (n0 + r0 + 32 * j) * 9 * CinB + scol * 16;
    const char* const wtB = (const char*)wt;
    auto stageB = [&](int tbv, int buf) {
        u16* lb = Bs + buf * BSZ + t * 8;
        #pragma unroll
        for (int j = 0; j < NB_B; j++)
            async_copy16(lb + j * 2048, (const u16*)(wtB + (tbv + vB[j])));
    };

    // per-thread A pixel base (tap 0,0)
    int pBase[4];
    #pragma unroll
    for (int mt = 0; mt < 4; mt++) {
        int dm = wm * 64 + mt * 16 + l16;          // m - m0
        pBase[mt] = (dm >> logW) * Wp + (dm & (W - 1));
    }

    floatx4 acc[4][NT];
    #pragma unroll
    for (int i = 0; i < 4; i++)
        #pragma unroll
        for (int j = 0; j < NT; j++)
            acc[i][j] = (floatx4){0.f, 0.f, 0.f, 0.f};

    const int sw = (l16 & 7) * 8;
    const char* const AhB = (const char*)Ah;

    stageB(0, 0);
    __syncthreads();                       // halo + B(0) ready

    int cur = 0, tb = 128;
    int pOff = 0, c3 = 0, cb = 0;
    for (int it = 0; it < T; it++) {
        if (it + 1 < T) { stageB(tb, cur ^ 1); tb += 128; }
        const int pO = pOff, cbv = cb;
        // advance (cin-block fastest, then tap lexicographic)
        cb += 128;
        if (cb == CinB) {
            cb = 0;
            pOff += (c3 == 2) ? (Wp - 2) : 1;
            c3 = (c3 == 2) ? 0 : c3 + 1;
        }

        // A fragments from resident halo (swizzled ds_read)
        bf16x8 af[2][4];
        #pragma unroll
        for (int mt = 0; mt < 4; mt++) {
            int p  = pBase[mt] + pO;
            int pc = p & 7;
            int ab = p * CinB + cbv;
            #pragma unroll
            for (int kk2 = 0; kk2 < 2; kk2++) {
                int kq = kk2 * 4 + quad;
                af[kk2][mt] = *(const bf16x8*)(AhB + ab + ((kq ^ pc) << 4));
            }
        }

        const u16* Bb = Bs + cur * BSZ;
        #pragma unroll
        for (int kk2 = 0; kk2 < 2; kk2++) {
            int cbo = kk2 * 32 + quad * 8;
            bf16x8 bfv[NT];
            #pragma unroll
            for (int nt = 0; nt < NT; nt++)
                bfv[nt] = *(const bf16x8*)(Bb + (wn * WC + nt * 16 + l16) * 64 + (cbo ^ sw));
            #pragma unroll
            for (int mt = 0; mt < 4; mt++)
                #pragma unroll
                for (int nt = 0; nt < NT; nt++)
                    acc[mt][nt] = __builtin_amdgcn_mfma_f32_16x16x32_bf16(
                        af[kk2][mt], bfv[nt], acc[mt][nt], 0, 0, 0);
        }
        __syncthreads();                   // B prefetch done + reads of cur done
        cur ^= 1;
    }

    const int ngb = n0 + wn * WC + l16;
    float bzv[NT];
    #pragma unroll
    for (int nt = 0; nt < NT; nt++) bzv[nt] = bias[ngb + nt * 16];
    const int Cout = BN;                     // Cout == BN for halo layers
    const int H = W;

    if (poolMode) {
        const int Hpo = (H >> 1) + 2;
        if (logW == 5) {            // W=32: y-partner = mt+2, in-lane
            #pragma unroll
            for (int mt = 0; mt < 2; mt++)
                #pragma unroll
                for (int rp = 0; rp < 2; rp++) {
                    int m1 = m0 + wm * 64 + mt * 16 + quad * 4 + 2 * rp;
                    int bb = m1 >> logHW;
                    int rm = m1 & (HW - 1);
                    int yp = (rm >> logW) >> 1;
                    int xp = (rm & (W - 1)) >> 1;
                    u16* op = out + (size_t)((bb * Hpo + yp + 1) * Hpo + xp + 1) * Cout + ngb;
                    #pragma unroll
                    for (int nt = 0; nt < NT; nt++) {
                        float v = fmaxf(
                            fmaxf(acc[mt][nt][2 * rp], acc[mt][nt][2 * rp + 1]),
                            fmaxf(acc[mt + 2][nt][2 * rp], acc[mt + 2][nt][2 * rp + 1]));
                        op[nt * 16] = f2bf(fmaxf(v + bzv[nt], 0.f));
                    }
                }
        } else {                    // W=16: y-partner = mt+1, in-lane
            #pragma unroll
            for (int mtp = 0; mtp < 2; mtp++)
                #pragma unroll
                for (int rp = 0; rp < 2; rp++) {
                    int mt = 2 * mtp;
                    int m1 = m0 + wm * 64 + mt * 16 + quad * 4 + 2 * rp;
                    int bb = m1 >> logHW;
                    int rm = m1 & (HW - 1);
                    int yp = (rm >> logW) >> 1;
                    int xp = (rm & (W - 1)) >> 1;
                    u16* op = out + (size_t)((bb * Hpo + yp + 1) * Hpo + xp + 1) * Cout + ngb;
                    #pragma unroll
                    for (int nt = 0; nt < NT; nt++) {
                        float v = fmaxf(
                            fmaxf(acc[mt][nt][2 * rp], acc[mt][nt][2 * rp + 1]),
                            fmaxf(acc[mt + 1][nt][2 * rp], acc[mt + 1][nt][2 * rp + 1]));
                        op[nt * 16] = f2bf(fmaxf(v + bzv[nt], 0.f));
                    }
                }
        }
        return;
    }

    #pragma unroll
    for (int mt = 0; mt < 4; mt++) {
        #pragma unroll
        for (int r = 0; r < 4; r++) {
            int mg = m0 + wm * 64 + mt * 16 + quad * 4 + r;
            size_t obase;
            if (outPad) {
                int bb = mg >> logHW;
                int rm = mg & (HW - 1);
                int y  = rm >> logW;
                int xx = rm & (W - 1);
                obase = (size_t)((bb * Wp + y + 1) * Wp + xx + 1) * Cout;
            } else {
                obase = (size_t)mg * Cout;
            }
            u16* op = out + obase + ngb;
            #pragma unroll
            for (int nt = 0; nt < NT; nt++)
                op[nt * 16] = f2bf(fmaxf(acc[mt][nt][r] + bzv[nt], 0.f));
        }
    }
}

// sum split partials + bias + relu -> bf16 NHWC (padded out optional)
__global__ void reduce_split(const float* __restrict__ partial,
                             const float* __restrict__ bias, u16* __restrict__ out,
                             int MN, int C, int logC, int splitN, size_t pstride,
                             int H, int logHW, int logW, int outPad)
{
    int i4 = (blockIdx.x * 256 + threadIdx.x) * 4;
    if (i4 >= MN) return;
    float4 s = *(const float4*)(partial + i4);
    for (int sp = 1; sp < splitN; sp++) {
        float4 p = *(const float4*)(partial + (size_t)sp * pstride + i4);
        s.x += p.x; s.y += p.y; s.z += p.z; s.w += p.w;
    }
    int n = i4 & (C - 1);
    int m = i4 >> logC;
    size_t obase;
    if (outPad) {
        int Wp = H + 2;
        int b  = m >> logHW;
        int rm = m & ((1 << logHW) - 1);
        int y  = rm >> logW;
        int xx = rm & (H - 1);
        obase = (size_t)((b * Wp + y + 1) * Wp + xx + 1) * C;
    } else {
        obase = (size_t)m * C;
    }
    ushort4 o;
    o.x = f2bf(fmaxf(s.x + bias[n + 0], 0.f));
    o.y = f2bf(fmaxf(s.y + bias[n + 1], 0.f));
    o.z = f2bf(fmaxf(s.z + bias[n + 2], 0.f));
    o.w = f2bf(fmaxf(s.w + bias[n + 3], 0.f));
    *(ushort4*)(out + obase + n) = o;
}

// sum split partials + bias + relu + 2x2 maxpool -> bf16 (padded optional)
__global__ void reduce_pool(const float* __restrict__ partial,
                            const float* __restrict__ bias, u16* __restrict__ out,
                            int total4, int C, int splitN, size_t pstride,
                            int H, int outPad)
{
    int idx = blockIdx.x * 256 + threadIdx.x;
    if (idx >= total4) return;
    int c4 = idx % (C / 4);
    int p  = idx / (C / 4);
    int Ho = H >> 1;
    int xp = p % Ho; p /= Ho;
    int yp = p % Ho;
    int b  = p / Ho;
    int n  = c4 * 4;
    float4 best;
    bool first = true;
    #pragma unroll
    for (int dy = 0; dy < 2; dy++)
        #pragma unroll
        for (int dx = 0; dx < 2; dx++) {
            int m = (b * H + 2 * yp + dy) * H + 2 * xp + dx;
            const float* q = partial + (size_t)m * C + n;
            float4 s = *(const float4*)q;
            for (int sp = 1; sp < splitN; sp++) {
                float4 pp = *(const float4*)(q + (size_t)sp * pstride);
                s.x += pp.x; s.y += pp.y; s.z += pp.z; s.w += pp.w;
            }
            if (first) { best = s; first = false; }
            else {
                best.x = fmaxf(best.x, s.x); best.y = fmaxf(best.y, s.y);
                best.z = fmaxf(best.z, s.z); best.w = fmaxf(best.w, s.w);
            }
        }
    size_t obase;
    if (outPad) {
        int Hpo = Ho + 2;
        obase = (size_t)((b * Hpo + yp + 1) * Hpo + xp + 1) * C;
    } else {
        obase = (size_t)((b * Ho + yp) * Ho + xp) * C;
    }
    ushort4 o;
    o.x = f2bf(fmaxf(best.x + bias[n + 0], 0.f));
    o.y = f2bf(fmaxf(best.y + bias[n + 1], 0.f));
    o.z = f2bf(fmaxf(best.z + bias[n + 2], 0.f));
    o.w = f2bf(fmaxf(best.w + bias[n + 3], 0.f));
    *(ushort4*)(out + obase + n) = o;
}

// ---------------------------------------------------------------------------
// Generic small GEMM: out[M,N] = act(A[M,K](bf16) @ Bt[N,K](bf16)^T + bias)
// ---------------------------------------------------------------------------
template <bool RELU, bool OUTBF>
__global__ __launch_bounds__(256) void gemm64(
    const u16* __restrict__ A, const u16* __restrict__ Bt,
    const float* __restrict__ bias, void* __restrict__ outv,
    int M, int N, int K)
{
    constexpr int LDP = 72;
    __shared__ u16 As[64 * LDP];
    __shared__ u16 Bs[64 * LDP];

    const int nb = N >> 6;
    const int m0 = (blockIdx.x / nb) * 64;
    const int n0 = (blockIdx.x % nb) * 64;
    const int t = threadIdx.x, lane = t & 63, wave = t >> 6;
    const int quad = lane >> 4, l16 = lane & 15;
    const int wm = wave >> 1, wn = wave & 1;
    const int col8 = t & 7, r0 = t >> 3;

    floatx4 acc[2][2];
    #pragma unroll
    for (int i = 0; i < 2; i++)
        #pragma unroll
        for (int j = 0; j < 2; j++)
            acc[i][j] = (floatx4){0.f, 0.f, 0.f, 0.f};

    for (int kb = 0; kb < K; kb += 64) {
        #pragma unroll
        for (int j = 0; j < 2; j++) {
            int row = r0 + 32 * j;
            *(uint4*)(As + row * LDP + col8 * 8) =
                *(const uint4*)(A + (size_t)(m0 + row) * K + kb + col8 * 8);
            *(uint4*)(Bs + row * LDP + col8 * 8) =
                *(const uint4*)(Bt + (size_t)(n0 + row) * K + kb + col8 * 8);
        }
        __syncthreads();
        #pragma unroll
        for (int kk = 0; kk < 64; kk += 32) {
            bf16x8 af[2], bfv[2];
            #pragma unroll
            for (int mt = 0; mt < 2; mt++)
                af[mt] = *(const bf16x8*)(As + (wm * 32 + mt * 16 + l16) * LDP + kk + quad * 8);
            #pragma unroll
            for (int nt = 0; nt < 2; nt++)
                bfv[nt] = *(const bf16x8*)(Bs + (wn * 32 + nt * 16 + l16) * LDP + kk + quad * 8);
            #pragma unroll
            for (int mt = 0; mt < 2; mt++)
                #pragma unroll
                for (int nt = 0; nt < 2; nt++)
                    acc[mt][nt] = __builtin_amdgcn_mfma_f32_16x16x32_bf16(
                        af[mt], bfv[nt], acc[mt][nt], 0, 0, 0);
        }
        __syncthreads();
    }
    #pragma unroll
    for (int mt = 0; mt < 2; mt++) {
        #pragma unroll
        for (int nt = 0; nt < 2; nt++) {
            #pragma unroll
            for (int r = 0; r < 4; r++) {
                int mg = m0 + wm * 32 + mt * 16 + quad * 4 + r;
                int ng = n0 + wn * 32 + nt * 16 + l16;
                float v = acc[mt][nt][r] + bias[ng];
                if (RELU) v = fmaxf(v, 0.f);
                if (OUTBF) ((u16*)outv)[(size_t)mg * N + ng] = f2bf(v);
                else       ((float*)outv)[(size_t)mg * N + ng] = v;
            }
        }
    }
}

// ---------------------------------------------------------------------------
__global__ __launch_bounds__(256) void graph_tile(
    const float* __restrict__ low, const int* __restrict__ target,
    float* __restrict__ gpre, float* __restrict__ ggt)
{
    __shared__ float Al[64 * 132];
    __shared__ float Bl[128 * 68];
    const int t = threadIdx.x;
    const int gr0 = (blockIdx.x >> 3) * 64;
    const int gc0 = (blockIdx.x & 7) * 64;

    #pragma unroll
    for (int j = 0; j < 32; j++) {
        int flat = t + 256 * j;
        int k = flat & 127;
        int rc = flat >> 7;
        Al[rc * 132 + k] = low[(size_t)(gr0 + rc) * 128 + k];
        Bl[k * 68 + rc]  = low[(size_t)(gc0 + rc) * 128 + k];
    }
    __syncthreads();

    const int tx = t & 15, ty = t >> 4;
    float acc[4][4];
    #pragma unroll
    for (int r = 0; r < 4; r++)
        #pragma unroll
        for (int c = 0; c < 4; c++) acc[r][c] = 0.f;

    for (int k = 0; k < 128; k++) {
        float a[4], b[4];
        #pragma unroll
        for (int r = 0; r < 4; r++) a[r] = Al[(ty * 4 + r) * 132 + k];
        #pragma unroll
        for (int c = 0; c < 4; c++) b[c] = Bl[k * 68 + tx * 4 + c];
        #pragma unroll
        for (int r = 0; r < 4; r++)
            #pragma unroll
            for (int c = 0; c < 4; c++) acc[r][c] += a[r] * b[c];
    }
    #pragma unroll
    for (int r = 0; r < 4; r++) {
        int row = gr0 + ty * 4 + r;
        int tr  = target[row];
        float4 gp, gg;
        float* pp = (float*)&gp;
        float* gg_ = (float*)&gg;
        #pragma unroll
        for (int c = 0; c < 4; c++) {
            pp[c]  = 1.f / (1.f + __expf(-acc[r][c]));
            gg_[c] = (tr == target[gc0 + tx * 4 + c]) ? 1.f : 0.f;
        }
        *(float4*)(gpre + (size_t)row * 512 + gc0 + tx * 4) = gp;
        *(float4*)(ggt  + (size_t)row * 512 + gc0 + tx * 4) = gg;
    }
}

// ---------------------------------------------------------------------------
__global__ __launch_bounds__(256) void cls_kernel(
    const u16* __restrict__ feat, const float* __restrict__ w,
    const float* __restrict__ bias, float* __restrict__ out)
{
    __shared__ float ws[5120];
    const int t = threadIdx.x;
    for (int i = t; i < 5120; i += 256) ws[i] = w[i];
    __syncthreads();
    const int lane = t & 63;
    const int row  = blockIdx.x * 4 + (t >> 6);
    float a[10];
    #pragma unroll
    for (int j = 0; j < 10; j++) a[j] = 0.f;
    #pragma unroll
    for (int i = 0; i < 8; i++) {
        int k = i * 64 + lane;
        float f = bf2f(feat[(size_t)row * 512 + k]);
        #pragma unroll
        for (int j = 0; j < 10; j++) a[j] += f * ws[k * 10 + j];
    }
    #pragma unroll
    for (int j = 0; j < 10; j++)
        #pragma unroll
        for (int off = 32; off > 0; off >>= 1)
            a[j] += __shfl_down(a[j], off, 64);
    if (lane == 0) {
        #pragma unroll
        for (int j = 0; j < 10; j++) out[row * 10 + j] = a[j] + bias[j];
    }
}

// ---------------------------------------------------------------------------
extern "C" void kernel_launch(void* const* d_in, const int* in_sizes, int n_in,
                              void* d_out, int out_size, void* d_ws, size_t ws_size,
                              hipStream_t stream)
{
    const float* x      = (const float*)d_in[0];
    const int*   target = (const int*)d_in[1];
    const float* conv_w[13];
    const float* conv_b[13];
    for (int i = 0; i < 13; i++) {
        conv_w[i] = (const float*)d_in[2 + 2 * i];
        conv_b[i] = (const float*)d_in[3 + 2 * i];
    }
    const float* lin1_w = (const float*)d_in[28];
    const float* lin1_b = (const float*)d_in[29];
    const float* lin2_w = (const float*)d_in[30];
    const float* lin2_b = (const float*)d_in[31];
    const float* cls_w  = (const float*)d_in[32];
    const float* cls_b  = (const float*)d_in[33];
    float* out = (float*)d_out;

    static const int cin_arr[13]  = {3, 64, 64, 128, 128, 256, 256, 256, 512, 512, 512, 512, 512};
    static const int cout_arr[13] = {64, 64, 128, 128, 256, 256, 256, 512, 512, 512, 512, 512, 512};

    char* ws = (char*)d_ws;
    size_t off = 0;
    const size_t R0SZ = (size_t)512 * 34 * 34 * 64 * 2;
    const size_t R1SZ = (size_t)512 * 34 * 34 * 64 * 2;
    char* R0raw = ws + off; off += R0SZ;
    char* R1raw = ws + off; off += R1SZ;
    u16* R0 = (u16*)R0raw;
    u16* R1 = (u16*)R1raw;
    float* PA = (float*)(R0raw + 20971520);
    float* PB = (float*)(R1raw + 20971520);
    u16* wt[13];
    for (int i = 1; i < 13; i++) {
        wt[i] = (u16*)(ws + off);
        off += (size_t)cout_arr[i] * 9 * cin_arr[i] * 2;
    }
    u16* wtl1 = (u16*)(ws + off); off += (size_t)256 * 512 * 2;
    u16* wtl2 = (u16*)(ws + off); off += (size_t)128 * 256 * 2;
    u16* hbuf = (u16*)(ws + off); off += (size_t)512 * 256 * 2;
    float* lowbuf = (float*)(ws + off); off += (size_t)512 * 128 * 4;

    // ---- single merged repack launch (12 conv + 2 lin), LDS-staged ----
    RepackArgs ra;
    int nb = 0, blk = 0;
    ra.startBlk[0] = 0;
    for (int i = 1; i < 13; i++) {
        ra.src[nb] = conv_w[i];
        ra.dst[nb] = wt[i];
        ra.p1[nb] = cin_arr[i];
        ra.p2[nb] = 0;
        blk += cout_arr[i] * cin_arr[i] / 1024;   // 9216 elems per block
        nb++; ra.startBlk[nb] = blk;
    }
    ra.src[nb] = lin1_w; ra.dst[nb] = wtl1; ra.p1[nb] = 512; ra.p2[nb] = 256;
    blk += (512 / 64) * (256 / 64);
    nb++; ra.startBlk[nb] = blk;
    ra.src[nb] = lin2_w; ra.dst[nb] = wtl2; ra.p1[nb] = 256; ra.p2[nb] = 128;
    blk += (256 / 64) * (128 / 64);
    nb++; ra.startBlk[nb] = blk;
    ra.nseg = nb;
    repack_all<<<blk, 256, 0, stream>>>(ra);

    auto zh = [&](u16* buf, int Hp, int C) {
        int total8 = 512 * (4 * Hp - 4) * (C / 8);
        zero_halo<<<(total8 + 255) / 256, 256, 0, stream>>>(buf, Hp, C, total8);
    };
    auto launch_conv = [&](int li, int Hl, int bm, int bn, u16* inb, u16* outb,
                           float* part, int splitN, int outPad, int poolMode) {
        int Cin = cin_arr[li], Cout = cout_arr[li];
        int M = 512 * Hl * Hl;
        int logW = __builtin_ctz(Hl);
        int logHW = 2 * logW;
        size_t pstride = (size_t)M * Cout;
        int grid = (M / bm) * (Cout / bn) * splitN;
        if (bm == 256) {
            conv_gemm<256, 64><<<grid, 256, 0, stream>>>(
                inb, wt[li], conv_b[li], outb, part, pstride,
                Hl, Cin, Cout, logHW, logW, splitN, outPad, poolMode);
        } else if (bn == 128) {
            conv_gemm<128, 128><<<grid, 256, 0, stream>>>(
                inb, wt[li], conv_b[li], outb, part, pstride,
                Hl, Cin, Cout, logHW, logW, splitN, outPad, poolMode);
        } else {
            conv_gemm<128, 64><<<grid, 256, 0, stream>>>(
                inb, wt[li], conv_b[li], outb, part, pstride,
                Hl, Cin, Cout, logHW, logW, splitN, outPad, poolMode);
        }
    };
    auto launch_reduce = [&](int li, int Hl, u16* outb, float* part, int splitN, int outPad) {
        int Cout = cout_arr[li];
        int M = 512 * Hl * Hl;
        int logW = __builtin_ctz(Hl);
        size_t pstride = (size_t)M * Cout;
        int MN = M * Cout;
        reduce_split<<<(MN / 4 + 255) / 256, 256, 0, stream>>>(
            part, conv_b[li], outb, MN, Cout, __builtin_ctz(Cout),
            splitN, pstride, Hl, 2 * logW, logW, outPad);
    };
    auto launch_reduce_pool = [&](int li, int Hl, u16* outb, float* part, int splitN, int outPad) {
        int Cout = cout_arr[li];
        int M = 512 * Hl * Hl;
        size_t pstride = (size_t)M * Cout;
        int total4 = 512 * (Hl / 2) * (Hl / 2) * Cout / 4;
        reduce_pool<<<(total4 + 255) / 256, 256, 0, stream>>>(
            part, conv_b[li], outb, total4, Cout, splitN, pstride, Hl, outPad);
    };

    zh(R0, 34, 64);
    conv0_kernel<<<512 * 8, 256, 0, stream>>>(x, conv_w[0], conv_b[0], R0);

    zh(R1, 18, 64);
    conv_halo<256, 64, 32, 64><<<2048, 256, 0, stream>>>(
        R0, wt[1], conv_b[1], R1, 0, 1);                     // L1 + pool (halo)
    zh(R0, 18, 128);
    conv_halo<128, 128, 16, 64><<<1024, 256, 0, stream>>>(
        R1, wt[2], conv_b[2], R0, 1, 0);                     // L2 (halo)
    zh(R1, 10, 128);
    conv_halo<128, 128, 16, 128><<<1024, 256, 0, stream>>>(
        R0, wt[3], conv_b[3], R1, 0, 1);                     // L3 + pool (halo)
    zh(R0, 10, 256);
    launch_conv(4, 8, 128, 128, R1, R0, nullptr, 1, 1, 0);   // L4
    zh(R1, 10, 256);
    launch_conv(5, 8, 128, 128, R0, R1, nullptr, 1, 1, 0);   // L5
    zh(R0, 6, 256);
    launch_conv(6, 8, 128, 128, R1, R0, nullptr, 1, 0, 1);   // L6 + pool
    zh(R1, 6, 512);
    launch_conv(7, 4, 128, 128, R0, R1, PB, 2, 1, 0);        // L7 split2
    launch_reduce(7, 4, R1, PB, 2, 1);
    zh(R0, 6, 512);
    launch_conv(8, 4, 128, 128, R1, R0, PA, 2, 1, 0);        // L8 split2
    launch_reduce(8, 4, R0, PA, 2, 1);
    zh(R1, 4, 512);
    launch_conv(9, 4, 128, 128, R0, R1, PB, 2, 0, 0);        // L9 split2
    launch_reduce_pool(9, 4, R1, PB, 2, 1);
    zh(R0, 4, 512);
    launch_conv(10, 2, 128, 64, R1, R0, PA, 4, 1, 0);        // L10 split4
    launch_reduce(10, 2, R0, PA, 4, 1);
    zh(R1, 4, 512);
    launch_conv(11, 2, 128, 64, R0, R1, PB, 4, 1, 0);        // L11 split4
    launch_reduce(11, 2, R1, PB, 4, 1);
    launch_conv(12, 2, 128, 64, R1, R0, PA, 4, 0, 0);        // L12 split4
    launch_reduce_pool(12, 2, R0, PA, 4, 0);                 // feat = R0 [512,512]

    u16* feat = R0;
    gemm64<true, true><<<(512 / 64) * (256 / 64), 256, 0, stream>>>(
        feat, wtl1, lin1_b, hbuf, 512, 256, 512);
    gemm64<false, false><<<(512 / 64) * (128 / 64), 256, 0, stream>>>(
        hbuf, wtl2, lin2_b, lowbuf, 512, 128, 256);
    graph_tile<<<64, 256, 0, stream>>>(lowbuf, target, out + 5120, out + 5120 + 262144);
    cls_kernel<<<128, 256, 0, stream>>>(feat, cls_w, cls_b, out);
}

// Round 6
// 672.804 us; speedup vs baseline: 2.3621x; 1.0154x over previous
//
#include <hip/hip_runtime.h>

typedef unsigned short u16;
typedef __bf16 bf16x8 __attribute__((ext_vector_type(8)));
typedef float floatx4 __attribute__((ext_vector_type(4)));

__device__ inline u16 f2bf(float f) {
    return __builtin_bit_cast(u16, (__bf16)f);   // v_cvt RNE, 1 op
}
__device__ inline float bf2f(u16 h) {
    return __uint_as_float(((unsigned int)h) << 16);
}

// async global->LDS, 16B per lane. LDS dest must be wave-uniform base + lane*16.
__device__ __forceinline__ void async_copy16(u16* lds, const u16* g) {
    __builtin_amdgcn_global_load_lds(
        (const __attribute__((address_space(1))) unsigned int*)(uintptr_t)g,
        (__attribute__((address_space(3))) unsigned int*)(unsigned int)(uintptr_t)lds,
        16, 0, 0);
}

// ---------------------------------------------------------------------------
// zero ONLY the 1-px halo ring of a padded NHWC buffer [512][Hp][Hp][C]
// ---------------------------------------------------------------------------
__global__ void zero_halo(u16* __restrict__ buf, int Hp, int C, int total8)
{
    int i = blockIdx.x * 256 + threadIdx.x;
    if (i >= total8) return;
    int c8 = i % (C / 8);
    int p  = i / (C / 8);
    int ring = 4 * Hp - 4;
    int h = p % ring;
    int b = p / ring;
    int y, x;
    if (h < Hp)              { y = 0;              x = h; }
    else if (h < 2 * Hp)     { y = Hp - 1;         x = h - Hp; }
    else if (h < 3 * Hp - 2) { y = h - 2 * Hp + 1; x = 0; }
    else                     { y = h - 3 * Hp + 3; x = Hp - 1; }
    uint4 z = make_uint4(0u, 0u, 0u, 0u);
    *(uint4*)(buf + ((size_t)((b * Hp + y) * Hp + x) * C) + c8 * 8) = z;
}

// ---------------------------------------------------------------------------
// Layer 0 via MFMA: GEMM M=512*1024 px, N=64, K=27 padded to 32.
// Per block: 256 px (8 rows of one image). fp32 input strip [3][10][36] staged
// in LDS once; A-fragments gathered via a 32-entry tap-offset table and
// converted to bf16; B (64x27 weights) lives in 16 VGPRs for the whole block;
// 16 MFMAs; fused bias+ReLU+bf16 epilogue into PADDED NHWC [512][34][34][64].
// k>=27 lanes: A and B both zeroed (B load predicated - o=63 would be OOB).
// ---------------------------------------------------------------------------
__global__ __launch_bounds__(256) void conv0_mfma(
    const float* __restrict__ x, const float* __restrict__ w,
    const float* __restrict__ bias, u16* __restrict__ out)
{
    __shared__ __align__(16) float xsf[3 * 10 * 36];
    __shared__ int tab[32];
    const int t  = threadIdx.x;
    const int b  = blockIdx.x >> 2;
    const int y0 = (blockIdx.x & 3) * 8;

    // stage input strip rows y0-1 .. y0+8, cols -1..34 (zero padded)
    for (int i = t; i < 3 * 10 * 36; i += 256) {
        int ci  = i / 360;
        int rem = i % 360;
        int r   = rem / 36;
        int c   = rem % 36;
        int gy  = y0 - 1 + r;
        int gx  = c - 1;
        float v = 0.f;
        if ((unsigned)gy < 32u && (unsigned)gx < 32u)
            v = x[((b * 3 + ci) * 32 + gy) * 32 + gx];
        xsf[i] = v;
    }
    if (t < 32) {
        int k = t, off = 0;
        if (k < 27) {
            int ci = k / 9;
            int r9 = k - ci * 9;
            int rr = r9 / 3;
            int cc = r9 - rr * 3;
            off = (ci * 10 + rr) * 36 + cc;
        }
        tab[t] = off;            // k>=27 -> 0 (valid addr; value masked below)
    }

    const int lane = t & 63;
    const int wv   = t >> 6;
    const int quad = lane >> 4;
    const int l16  = lane & 15;
    const int q8   = quad * 8;

    // B fragments: 4 n-tiles x 8 k-values, predicated load (k<27)
    bf16x8 bf[4];
    #pragma unroll
    for (int nt = 0; nt < 4; nt++) {
        int col = nt * 16 + l16;
        u16 hh[8];
        #pragma unroll
        for (int j = 0; j < 8; j++) {
            int k = q8 + j;
            float wv_ = (k < 27) ? w[col * 27 + k] : 0.f;
            hh[j] = f2bf(wv_);
        }
        #pragma unroll
        for (int j = 0; j < 8; j++) ((u16*)&bf[nt])[j] = hh[j];
    }
    float bzv[4];
    #pragma unroll
    for (int nt = 0; nt < 4; nt++) bzv[nt] = bias[nt * 16 + l16];

    __syncthreads();

    int tb_[8];
    #pragma unroll
    for (int j = 0; j < 8; j++) tb_[j] = tab[q8 + j];

    // A fragments: 4 m-tiles of 16 pixels each
    bf16x8 af[4];
    #pragma unroll
    for (int mt = 0; mt < 4; mt++) {
        int dm   = wv * 64 + mt * 16 + l16;
        int yloc = dm >> 5;
        int xx   = dm & 31;
        int bix  = yloc * 36 + xx;
        u16 hh[8];
        #pragma unroll
        for (int j = 0; j < 8; j++) hh[j] = f2bf(xsf[bix + tb_[j]]);
        if (quad == 3) {
            #pragma unroll
            for (int j = 3; j < 8; j++) hh[j] = 0;   // k = 27..31
        }
        #pragma unroll
        for (int j = 0; j < 8; j++) ((u16*)&af[mt])[j] = hh[j];
    }

    floatx4 acc[4][4];
    #pragma unroll
    for (int i = 0; i < 4; i++)
        #pragma unroll
        for (int j = 0; j < 4; j++)
            acc[i][j] = (floatx4){0.f, 0.f, 0.f, 0.f};

    #pragma unroll
    for (int mt = 0; mt < 4; mt++)
        #pragma unroll
        for (int nt = 0; nt < 4; nt++)
            acc[mt][nt] = __builtin_amdgcn_mfma_f32_16x16x32_bf16(
                af[mt], bf[nt], acc[mt][nt], 0, 0, 0);

    // epilogue: bias + relu -> bf16 padded NHWC
    #pragma unroll
    for (int mt = 0; mt < 4; mt++) {
        #pragma unroll
        for (int r = 0; r < 4; r++) {
            int p  = wv * 64 + mt * 16 + quad * 4 + r;
            int y  = y0 + (p >> 5);
            int xx = p & 31;
            u16* op = out + (size_t)((b * 34 + y + 1) * 34 + xx + 1) * 64 + l16;
            #pragma unroll
            for (int nt = 0; nt < 4; nt++)
                op[nt * 16] = f2bf(fmaxf(acc[mt][nt][r] + bzv[nt], 0.f));
        }
    }
}

// ---------------------------------------------------------------------------
// Merged weight repack, LDS-staged so BOTH global sides are coalesced.
// ---------------------------------------------------------------------------
struct RepackArgs {
    const float* src[14];
    u16* dst[14];
    int p1[14];        // Cin (conv) or K (lin)
    int p2[14];        // 0 (conv) or N (lin)
    int startBlk[15];
    int nseg;
};

__global__ __launch_bounds__(256) void repack_all(RepackArgs a)
{
    __shared__ __align__(16) u16 lds[9216];
    int blk = blockIdx.x;
    int s = 0;
    #pragma unroll 1
    while (s + 1 < a.nseg && blk >= a.startBlk[s + 1]) s++;
    const int cb = blk - a.startBlk[s];
    const int t  = threadIdx.x;

    if (a.p2[s] == 0) {
        // ---- conv: block covers 9216 consecutive elements of src AND dst ----
        const int Cin = a.p1[s];
        const int logCin = __builtin_ctz(Cin);
        const float* src = a.src[s] + (size_t)cb * 9216;
        u16* dst = a.dst[s] + (size_t)cb * 9216;
        #pragma unroll
        for (int it = 0; it < 9; it++) {
            int j4 = it * 256 + t;                       // float4 index 0..2303
            float4 v = *(const float4*)(src + j4 * 4);
            ushort4 h;
            h.x = f2bf(v.x); h.y = f2bf(v.y); h.z = f2bf(v.z); h.w = f2bf(v.w);
            *(ushort4*)(lds + j4 * 4) = h;
        }
        __syncthreads();
        #pragma unroll
        for (int it = 0; it < 9; it++) {
            int o4   = (it * 256 + t) * 4;               // dst linear (co*9+sh)*Cin+ci
            int ci   = o4 & (Cin - 1);
            int rest = o4 >> logCin;                     // co*9 + sh
            int co   = rest / 9;
            int sh   = rest - co * 9;
            int sb   = (co << logCin) * 9 + ci * 9 + sh; // src-order LDS index
            ushort4 h;
            h.x = lds[sb]; h.y = lds[sb + 9]; h.z = lds[sb + 18]; h.w = lds[sb + 27];
            *(ushort4*)(dst + o4) = h;
        }
    } else {
        // ---- linear: 64x64 tile transpose f32[K][N] -> bf16[N][K] ----
        const int K = a.p1[s], N = a.p2[s];
        const int ntx = N >> 6;
        const int k0 = (cb / ntx) * 64, n0 = (cb % ntx) * 64;
        const float* src = a.src[s];
        u16* dst = a.dst[s];
        const int r = t >> 4, c4 = (t & 15) * 4;         // lds pitch 72 u16
        #pragma unroll
        for (int rr = 0; rr < 64; rr += 16) {
            float4 v = *(const float4*)(src + (size_t)(k0 + r + rr) * N + n0 + c4);
            u16* p = lds + (r + rr) * 72 + c4;
            p[0] = f2bf(v.x); p[1] = f2bf(v.y); p[2] = f2bf(v.z); p[3] = f2bf(v.w);
        }
        __syncthreads();
        #pragma unroll
        for (int it = 0; it < 2; it++) {
            int ov = it * 256 + t;                       // 0..511 output vec8s
            int n  = ov >> 3;
            int kq = (ov & 7) * 8;
            __align__(16) u16 h[8];
            #pragma unroll
            for (int j = 0; j < 8; j++) h[j] = lds[(kq + j) * 72 + n];
            *(uint4*)(dst + (size_t)(n0 + n) * K + k0 + kq) = *(uint4*)h;
        }
    }
}

// ---------------------------------------------------------------------------
// Conv shift-GEMM (deep layers), bf16 MFMA 16x16x32. Double-buffered LDS for
// A and B; STAGE(t+1) before compute(t); one __syncthreads per K-step.
// BM=128: 4 waves 2x2 (wave cols = BN/2). BM=256: 4 waves 4x1 (wave cols = BN).
// ---------------------------------------------------------------------------
template <int BM, int BN>
__global__ __launch_bounds__(256) void conv_gemm(
    const u16* __restrict__ in, const u16* __restrict__ wt,
    const float* __restrict__ bias, u16* __restrict__ out,
    float* __restrict__ partial, size_t pstride,
    int H, int Cin, int Cout, int logHW, int logW, int splitN,
    int outPad, int poolMode)
{
    constexpr int BK = 64;
    constexpr int WC = (BM == 256) ? BN : (BN / 2);   // wave cols
    constexpr int NT = WC / 16;
    constexpr int NB_A = BM / 32;
    constexpr int NB_B = BN / 32;
    constexpr int ASZ = BM * BK;
    constexpr int BSZ = BN * BK;
    __shared__ u16 As[2 * ASZ];
    __shared__ u16 Bs[2 * BSZ];

    const int Nblocks = Cout / BN;
    const int per = gridDim.x >> 3;
    const int bid = (blockIdx.x & 7) * per + (blockIdx.x >> 3);
    const int sp   = bid % splitN;
    const int tile = bid / splitN;
    const int m0 = (tile / Nblocks) * BM;
    const int n0 = (tile % Nblocks) * BN;

    const int t    = threadIdx.x;
    const int lane = t & 63;
    const int wave = t >> 6;
    const int quad = lane >> 4;
    const int l16  = lane & 15;
    const int wm   = (BM == 256) ? wave : (wave >> 1);
    const int wn   = (BM == 256) ? 0 : (wave & 1);
    const int W    = H;
    const int Wp   = H + 2;
    const int HW   = 1 << logHW;
    const int col8 = t & 7;
    const int r0   = t >> 3;
    const int scol = col8 ^ (r0 & 7);

    const int CinB = Cin * 2;

    int vA[NB_A];
    #pragma unroll
    for (int j = 0; j < NB_A; j++) {
        int m  = m0 + r0 + 32 * j;
        int b  = m >> logHW;
        int rm = m & (HW - 1);
        int y  = rm >> logW;
        int xx = rm & (W - 1);
        vA[j] = ((b * Wp + y + 1) * Wp + xx + 1) * CinB + scol * 16;
    }
    int vB[NB_B];
    #pragma unroll
    for (int j = 0; j < NB_B; j++)
        vB[j] = (n0 + r0 + 32 * j) * 9 * CinB + scol * 16;

    const int logKB = (Cin == 64) ? 0 : (Cin == 128) ? 1 : (Cin == 256) ? 2 : 3;
    const int KB  = 1 << logKB;
    const int T   = 9 * KB;
    const int len = T / splitN;
    const int it0 = sp * len;

    int s0 = it0 >> logKB;
    int c3 = s0 - (s0 / 3) * 3;
    int ta = ((s0 / 3 - 1) * Wp + (c3 - 1)) * CinB;
    int kb = (it0 & (KB - 1)) * 128;
    int tb = it0 * 128;

    const char* const inB = (const char*)in;
    const char* const wtB = (const char*)wt;

    floatx4 acc[4][NT];
    #pragma unroll
    for (int i = 0; i < 4; i++)
        #pragma unroll
        for (int j = 0; j < NT; j++)
            acc[i][j] = (floatx4){0.f, 0.f, 0.f, 0.f};

    const int sw = (l16 & 7) * 8;

    // stage iteration's tiles into buffer half `buf`
    auto stage = [&](int ua, int tbv, int buf) {
        u16* la = As + buf * ASZ + t * 8;
        u16* lb = Bs + buf * BSZ + t * 8;
        #pragma unroll
        for (int j = 0; j < NB_A; j++)
            async_copy16(la + j * 2048, (const u16*)(inB + (ua + vA[j])));
        #pragma unroll
        for (int j = 0; j < NB_B; j++)
            async_copy16(lb + j * 2048, (const u16*)(wtB + (tbv + vB[j])));
    };
    auto advance = [&]() {
        tb += 128;
        kb += 128;
        if (kb == CinB) {
            kb = 0;
            ta += (c3 == 2) ? (Wp - 2) * CinB : CinB;
            c3 = (c3 == 2) ? 0 : c3 + 1;
        }
    };

    // prologue: stage iter 0 into buf 0
    stage(ta + kb, tb, 0);
    advance();
    __syncthreads();                       // implicit vmcnt(0): buf0 ready

    int cur = 0;
    for (int it = 0; it < len; it++) {
        if (it + 1 < len) {                // prefetch next tile into other half
            stage(ta + kb, tb, cur ^ 1);
            advance();
        }
        const u16* Ab = As + cur * ASZ;
        const u16* Bb = Bs + cur * BSZ;
        #pragma unroll
        for (int kk = 0; kk < BK; kk += 32) {
            bf16x8 af[4], bfv[NT];
            int cbo = kk + quad * 8;
            #pragma unroll
            for (int mt = 0; mt < 4; mt++)
                af[mt] = *(const bf16x8*)(Ab + (wm * 64 + mt * 16 + l16) * 64 + (cbo ^ sw));
            #pragma unroll
            for (int nt = 0; nt < NT; nt++)
                bfv[nt] = *(const bf16x8*)(Bb + (wn * WC + nt * 16 + l16) * 64 + (cbo ^ sw));
            #pragma unroll
            for (int mt = 0; mt < 4; mt++)
                #pragma unroll
                for (int nt = 0; nt < NT; nt++)
                    acc[mt][nt] = __builtin_amdgcn_mfma_f32_16x16x32_bf16(
                        af[mt], bfv[nt], acc[mt][nt], 0, 0, 0);
        }
        __syncthreads();                   // drains vmcnt (prefetch) + lgkmcnt
        cur ^= 1;
    }

    const int ngb = n0 + wn * WC + l16;

    if (splitN > 1) {
        float* pout = partial + (size_t)sp * pstride;
        #pragma unroll
        for (int mt = 0; mt < 4; mt++)
            #pragma unroll
            for (int r = 0; r < 4; r++) {
                int mg = m0 + wm * 64 + mt * 16 + quad * 4 + r;
                float* op = pout + (size_t)mg * Cout + ngb;
                #pragma unroll
                for (int nt = 0; nt < NT; nt++)
                    op[nt * 16] = acc[mt][nt][r];
            }
        return;
    }

    float bzv[NT];
    #pragma unroll
    for (int nt = 0; nt < NT; nt++) bzv[nt] = bias[ngb + nt * 16];

    if (poolMode) {
        const int Hpo = (H >> 1) + 2;
        if (logW == 5) {            // W=32: y-partner = mt+2, in-lane
            #pragma unroll
            for (int mt = 0; mt < 2; mt++)
                #pragma unroll
                for (int rp = 0; rp < 2; rp++) {
                    int m1 = m0 + wm * 64 + mt * 16 + quad * 4 + 2 * rp;
                    int b  = m1 >> logHW;
                    int rm = m1 & (HW - 1);
                    int yp = (rm >> logW) >> 1;
                    int xp = (rm & (W - 1)) >> 1;
                    u16* op = out + (size_t)((b * Hpo + yp + 1) * Hpo + xp + 1) * Cout + ngb;
                    #pragma unroll
                    for (int nt = 0; nt < NT; nt++) {
                        float v = fmaxf(
                            fmaxf(acc[mt][nt][2 * rp], acc[mt][nt][2 * rp + 1]),
                            fmaxf(acc[mt + 2][nt][2 * rp], acc[mt + 2][nt][2 * rp + 1]));
                        op[nt * 16] = f2bf(fmaxf(v + bzv[nt], 0.f));
                    }
                }
        } else if (logW == 4) {     // W=16: y-partner = mt+1, in-lane
            #pragma unroll
            for (int mtp = 0; mtp < 2; mtp++)
                #pragma unroll
                for (int rp = 0; rp < 2; rp++) {
                    int mt = 2 * mtp;
                    int m1 = m0 + wm * 64 + mt * 16 + quad * 4 + 2 * rp;
                    int b  = m1 >> logHW;
                    int rm = m1 & (HW - 1);
                    int yp = (rm >> logW) >> 1;
                    int xp = (rm & (W - 1)) >> 1;
                    u16* op = out + (size_t)((b * Hpo + yp + 1) * Hpo + xp + 1) * Cout + ngb;
                    #pragma unroll
                    for (int nt = 0; nt < NT; nt++) {
                        float v = fmaxf(
                            fmaxf(acc[mt][nt][2 * rp], acc[mt][nt][2 * rp + 1]),
                            fmaxf(acc[mt + 1][nt][2 * rp], acc[mt + 1][nt][2 * rp + 1]));
                        op[nt * 16] = f2bf(fmaxf(v + bzv[nt], 0.f));
                    }
                }
        } else {                    // W=8: y-partner = quad+2 via shfl32
            #pragma unroll
            for (int mt = 0; mt < 4; mt++)
                #pragma unroll
                for (int rp = 0; rp < 2; rp++) {
                    int m1 = m0 + wm * 64 + mt * 16 + quad * 4 + 2 * rp;
                    int b  = m1 >> logHW;
                    int rm = m1 & (HW - 1);
                    int yp = (rm >> logW) >> 1;
                    int xp = (rm & (W - 1)) >> 1;
                    u16* op = out + (size_t)((b * Hpo + yp + 1) * Hpo + xp + 1) * Cout + ngb;
                    #pragma unroll
                    for (int nt = 0; nt < NT; nt++) {
                        float a = fmaxf(acc[mt][nt][2 * rp], acc[mt][nt][2 * rp + 1]);
                        float p = __shfl_xor(a, 32, 64);
                        float v = fmaxf(a, p);
                        if (quad < 2)
                            op[nt * 16] = f2bf(fmaxf(v + bzv[nt], 0.f));
                    }
                }
        }
        return;
    }

    #pragma unroll
    for (int mt = 0; mt < 4; mt++) {
        #pragma unroll
        for (int r = 0; r < 4; r++) {
            int mg = m0 + wm * 64 + mt * 16 + quad * 4 + r;
            size_t obase;
            if (outPad) {
                int b  = mg >> logHW;
                int rm = mg & (HW - 1);
                int y  = rm >> logW;
                int xx = rm & (W - 1);
                obase = (size_t)((b * Wp + y + 1) * Wp + xx + 1) * Cout;
            } else {
                obase = (size_t)mg * Cout;
            }
            u16* op = out + obase + ngb;
            #pragma unroll
            for (int nt = 0; nt < NT; nt++)
                op[nt * 16] = f2bf(fmaxf(acc[mt][nt][r] + bzv[nt], 0.f));
        }
    }
}

// ---------------------------------------------------------------------------
// Halo-staged conv GEMM for early layers (row-aligned tiles within one image).
// The (R+2)x(W+2)xCin input halo is ONE contiguous global range; staged ONCE
// per block (XOR-8 chunk swizzle via source permutation). K-loop stages only
// the small B tile (double-buffered). Cuts A-staging traffic ~6x vs re-staging
// per tap and makes the per-iter barrier wait tiny.
// ---------------------------------------------------------------------------
template <int BM, int BN, int W, int CIN>
__global__ __launch_bounds__(256) void conv_halo(
    const u16* __restrict__ in, const u16* __restrict__ wt,
    const float* __restrict__ bias, u16* __restrict__ out,
    int outPad, int poolMode)
{
    constexpr int BK = 64;
    constexpr int WC = (BM == 256) ? BN : (BN / 2);
    constexpr int NT = WC / 16;
    constexpr int NB_B = BN / 32;
    constexpr int BSZ = BN * BK;
    constexpr int Wp = W + 2;
    constexpr int R  = BM / W;                 // rows per tile (8)
    constexpr int P  = (R + 2) * Wp;           // halo pixels
    constexpr int CinB = CIN * 2;              // bytes per pixel
    constexpr int CH = CinB / 16;              // 16B chunks per pixel (>=8)
    constexpr int LOG_CH = (CH == 8) ? 3 : 4;
    constexpr int HALO_CHUNKS = P * CH;
    constexpr int ROUNDS = (HALO_CHUNKS + 255) / 256;
    constexpr int logW = (W == 32) ? 5 : 4;
    constexpr int logHW = 2 * logW;
    constexpr int HW = 1 << logHW;
    constexpr int KB = CIN / 64;
    constexpr int T  = 9 * KB;

    __shared__ __align__(16) u16 Ah[P * CH * 8];   // halo (u16 units)
    __shared__ __align__(16) u16 Bs[2 * BSZ];

    constexpr int Nblocks = 1;                  // Cout == BN for all uses
    static_assert(true, "");
    const int per = gridDim.x >> 3;
    const int bid = (blockIdx.x & 7) * per + (blockIdx.x >> 3);
    const int m0 = (bid / Nblocks) * BM;
    const int n0 = (bid % Nblocks) * BN;

    const int t    = threadIdx.x;
    const int lane = t & 63;
    const int wave = t >> 6;
    const int quad = lane >> 4;
    const int l16  = lane & 15;
    const int wm   = (BM == 256) ? wave : (wave >> 1);
    const int wn   = (BM == 256) ? 0 : (wave & 1);
    const int col8 = t & 7;
    const int r0   = t >> 3;
    const int scol = col8 ^ (r0 & 7);

    const int b  = m0 >> logHW;
    const int y0 = (m0 & (HW - 1)) >> logW;

    // ---- stage halo (contiguous global range, swizzled source) ----
    const char* hsrc = (const char*)in + (size_t)((b * Wp + y0) * Wp) * CinB;
    #pragma unroll
    for (int rd = 0; rd < ROUNDS; rd++) {
        int i = rd * 256 + t;
        if ((HALO_CHUNKS % 256 == 0) || i < HALO_CHUNKS) {
            int pp   = i >> LOG_CH;
            int si   = i ^ (pp & 7);               // XOR low 3 chunk bits
            async_copy16(Ah + i * 8, (const u16*)(hsrc + (size_t)si * 16));
        }
    }

    // ---- B staging setup (identical to conv_gemm) ----
    int vB[NB_B];
    #pragma unroll
    for (int j = 0; j < NB_B; j++)
        vB[j] = (n0 + r0 + 32 * j) * 9 * CinB + scol * 16;
    const char* const wtB = (const char*)wt;
    auto stageB = [&](int tbv, int buf) {
        u16* lb = Bs + buf * BSZ + t * 8;
        #pragma unroll
        for (int j = 0; j < NB_B; j++)
            async_copy16(lb + j * 2048, (const u16*)(wtB + (tbv + vB[j])));
    };

    // per-thread A pixel base (tap 0,0)
    int pBase[4];
    #pragma unroll
    for (int mt = 0; mt < 4; mt++) {
        int dm = wm * 64 + mt * 16 + l16;          // m - m0
        pBase[mt] = (dm >> logW) * Wp + (dm & (W - 1));
    }

    floatx4 acc[4][NT];
    #pragma unroll
    for (int i = 0; i < 4; i++)
        #pragma unroll
        for (int j = 0; j < NT; j++)
            acc[i][j] = (floatx4){0.f, 0.f, 0.f, 0.f};

    const int sw = (l16 & 7) * 8;
    const char* const AhB = (const char*)Ah;

    stageB(0, 0);
    __syncthreads();                       // halo + B(0) ready

    int cur = 0, tb = 128;
    int pOff = 0, c3 = 0, cb = 0;
    for (int it = 0; it < T; it++) {
        if (it + 1 < T) { stageB(tb, cur ^ 1); tb += 128; }
        const int pO = pOff, cbv = cb;
        // advance (cin-block fastest, then tap lexicographic)
        cb += 128;
        if (cb == CinB) {
            cb = 0;
            pOff += (c3 == 2) ? (Wp - 2) : 1;
            c3 = (c3 == 2) ? 0 : c3 + 1;
        }

        // A fragments from resident halo (swizzled ds_read)
        bf16x8 af[2][4];
        #pragma unroll
        for (int mt = 0; mt < 4; mt++) {
            int p  = pBase[mt] + pO;
            int pc = p & 7;
            int ab = p * CinB + cbv;
            #pragma unroll
            for (int kk2 = 0; kk2 < 2; kk2++) {
                int kq = kk2 * 4 + quad;
                af[kk2][mt] = *(const bf16x8*)(AhB + ab + ((kq ^ pc) << 4));
            }
        }

        const u16* Bb = Bs + cur * BSZ;
        #pragma unroll
        for (int kk2 = 0; kk2 < 2; kk2++) {
            int cbo = kk2 * 32 + quad * 8;
            bf16x8 bfv[NT];
            #pragma unroll
            for (int nt = 0; nt < NT; nt++)
                bfv[nt] = *(const bf16x8*)(Bb + (wn * WC + nt * 16 + l16) * 64 + (cbo ^ sw));
            #pragma unroll
            for (int mt = 0; mt < 4; mt++)
                #pragma unroll
                for (int nt = 0; nt < NT; nt++)
                    acc[mt][nt] = __builtin_amdgcn_mfma_f32_16x16x32_bf16(
                        af[kk2][mt], bfv[nt], acc[mt][nt], 0, 0, 0);
        }
        __syncthreads();                   // B prefetch done + reads of cur done
        cur ^= 1;
    }

    const int ngb = n0 + wn * WC + l16;
    float bzv[NT];
    #pragma unroll
    for (int nt = 0; nt < NT; nt++) bzv[nt] = bias[ngb + nt * 16];
    const int Cout = BN;                     // Cout == BN for halo layers
    const int H = W;

    if (poolMode) {
        const int Hpo = (H >> 1) + 2;
        if (logW == 5) {            // W=32: y-partner = mt+2, in-lane
            #pragma unroll
            for (int mt = 0; mt < 2; mt++)
                #pragma unroll
                for (int rp = 0; rp < 2; rp++) {
                    int m1 = m0 + wm * 64 + mt * 16 + quad * 4 + 2 * rp;
                    int bb = m1 >> logHW;
                    int rm = m1 & (HW - 1);
                    int yp = (rm >> logW) >> 1;
                    int xp = (rm & (W - 1)) >> 1;
                    u16* op = out + (size_t)((bb * Hpo + yp + 1) * Hpo + xp + 1) * Cout + ngb;
                    #pragma unroll
                    for (int nt = 0; nt < NT; nt++) {
                        float v = fmaxf(
                            fmaxf(acc[mt][nt][2 * rp], acc[mt][nt][2 * rp + 1]),
                            fmaxf(acc[mt + 2][nt][2 * rp], acc[mt + 2][nt][2 * rp + 1]));
                        op[nt * 16] = f2bf(fmaxf(v + bzv[nt], 0.f));
                    }
                }
        } else {                    // W=16: y-partner = mt+1, in-lane
            #pragma unroll
            for (int mtp = 0; mtp < 2; mtp++)
                #pragma unroll
                for (int rp = 0; rp < 2; rp++) {
                    int mt = 2 * mtp;
                    int m1 = m0 + wm * 64 + mt * 16 + quad * 4 + 2 * rp;
                    int bb = m1 >> logHW;
                    int rm = m1 & (HW - 1);
                    int yp = (rm >> logW) >> 1;
                    int xp = (rm & (W - 1)) >> 1;
                    u16* op = out + (size_t)((bb * Hpo + yp + 1) * Hpo + xp + 1) * Cout + ngb;
                    #pragma unroll
                    for (int nt = 0; nt < NT; nt++) {
                        float v = fmaxf(
                            fmaxf(acc[mt][nt][2 * rp], acc[mt][nt][2 * rp + 1]),
                            fmaxf(acc[mt + 1][nt][2 * rp], acc[mt + 1][nt][2 * rp + 1]));
                        op[nt * 16] = f2bf(fmaxf(v + bzv[nt], 0.f));
                    }
                }
        }
        return;
    }

    #pragma unroll
    for (int mt = 0; mt < 4; mt++) {
        #pragma unroll
        for (int r = 0; r < 4; r++) {
            int mg = m0 + wm * 64 + mt * 16 + quad * 4 + r;
            size_t obase;
            if (outPad) {
                int bb = mg >> logHW;
                int rm = mg & (HW - 1);
                int y  = rm >> logW;
                int xx = rm & (W - 1);
                obase = (size_t)((bb * Wp + y + 1) * Wp + xx + 1) * Cout;
            } else {
                obase = (size_t)mg * Cout;
            }
            u16* op = out + obase + ngb;
            #pragma unroll
            for (int nt = 0; nt < NT; nt++)
                op[nt * 16] = f2bf(fmaxf(acc[mt][nt][r] + bzv[nt], 0.f));
        }
    }
}

// sum split partials + bias + relu -> bf16 NHWC (padded out optional)
__global__ void reduce_split(const float* __restrict__ partial,
                             const float* __restrict__ bias, u16* __restrict__ out,
                             int MN, int C, int logC, int splitN, size_t pstride,
                             int H, int logHW, int logW, int outPad)
{
    int i4 = (blockIdx.x * 256 + threadIdx.x) * 4;
    if (i4 >= MN) return;
    float4 s = *(const float4*)(partial + i4);
    for (int sp = 1; sp < splitN; sp++) {
        float4 p = *(const float4*)(partial + (size_t)sp * pstride + i4);
        s.x += p.x; s.y += p.y; s.z += p.z; s.w += p.w;
    }
    int n = i4 & (C - 1);
    int m = i4 >> logC;
    size_t obase;
    if (outPad) {
        int Wp = H + 2;
        int b  = m >> logHW;
        int rm = m & ((1 << logHW) - 1);
        int y  = rm >> logW;
        int xx = rm & (H - 1);
        obase = (size_t)((b * Wp + y + 1) * Wp + xx + 1) * C;
    } else {
        obase = (size_t)m * C;
    }
    ushort4 o;
    o.x = f2bf(fmaxf(s.x + bias[n + 0], 0.f));
    o.y = f2bf(fmaxf(s.y + bias[n + 1], 0.f));
    o.z = f2bf(fmaxf(s.z + bias[n + 2], 0.f));
    o.w = f2bf(fmaxf(s.w + bias[n + 3], 0.f));
    *(ushort4*)(out + obase + n) = o;
}

// sum split partials + bias + relu + 2x2 maxpool -> bf16 (padded optional)
__global__ void reduce_pool(const float* __restrict__ partial,
                            const float* __restrict__ bias, u16* __restrict__ out,
                            int total4, int C, int splitN, size_t pstride,
                            int H, int outPad)
{
    int idx = blockIdx.x * 256 + threadIdx.x;
    if (idx >= total4) return;
    int c4 = idx % (C / 4);
    int p  = idx / (C / 4);
    int Ho = H >> 1;
    int xp = p % Ho; p /= Ho;
    int yp = p % Ho;
    int b  = p / Ho;
    int n  = c4 * 4;
    float4 best;
    bool first = true;
    #pragma unroll
    for (int dy = 0; dy < 2; dy++)
        #pragma unroll
        for (int dx = 0; dx < 2; dx++) {
            int m = (b * H + 2 * yp + dy) * H + 2 * xp + dx;
            const float* q = partial + (size_t)m * C + n;
            float4 s = *(const float4*)q;
            for (int sp = 1; sp < splitN; sp++) {
                float4 pp = *(const float4*)(q + (size_t)sp * pstride);
                s.x += pp.x; s.y += pp.y; s.z += pp.z; s.w += pp.w;
            }
            if (first) { best = s; first = false; }
            else {
                best.x = fmaxf(best.x, s.x); best.y = fmaxf(best.y, s.y);
                best.z = fmaxf(best.z, s.z); best.w = fmaxf(best.w, s.w);
            }
        }
    size_t obase;
    if (outPad) {
        int Hpo = Ho + 2;
        obase = (size_t)((b * Hpo + yp + 1) * Hpo + xp + 1) * C;
    } else {
        obase = (size_t)((b * Ho + yp) * Ho + xp) * C;
    }
    ushort4 o;
    o.x = f2bf(fmaxf(best.x + bias[n + 0], 0.f));
    o.y = f2bf(fmaxf(best.y + bias[n + 1], 0.f));
    o.z = f2bf(fmaxf(best.z + bias[n + 2], 0.f));
    o.w = f2bf(fmaxf(best.w + bias[n + 3], 0.f));
    *(ushort4*)(out + obase + n) = o;
}

// ---------------------------------------------------------------------------
// Generic small GEMM: out[M,N] = act(A[M,K](bf16) @ Bt[N,K](bf16)^T + bias)
// ---------------------------------------------------------------------------
template <bool RELU, bool OUTBF>
__global__ __launch_bounds__(256) void gemm64(
    const u16* __restrict__ A, const u16* __restrict__ Bt,
    const float* __restrict__ bias, void* __restrict__ outv,
    int M, int N, int K)
{
    constexpr int LDP = 72;
    __shared__ u16 As[64 * LDP];
    __shared__ u16 Bs[64 * LDP];

    const int nb = N >> 6;
    const int m0 = (blockIdx.x / nb) * 64;
    const int n0 = (blockIdx.x % nb) * 64;
    const int t = threadIdx.x, lane = t & 63, wave = t >> 6;
    const int quad = lane >> 4, l16 = lane & 15;
    const int wm = wave >> 1, wn = wave & 1;
    const int col8 = t & 7, r0 = t >> 3;

    floatx4 acc[2][2];
    #pragma unroll
    for (int i = 0; i < 2; i++)
        #pragma unroll
        for (int j = 0; j < 2; j++)
            acc[i][j] = (floatx4){0.f, 0.f, 0.f, 0.f};

    for (int kb = 0; kb < K; kb += 64) {
        #pragma unroll
        for (int j = 0; j < 2; j++) {
            int row = r0 + 32 * j;
            *(uint4*)(As + row * LDP + col8 * 8) =
                *(const uint4*)(A + (size_t)(m0 + row) * K + kb + col8 * 8);
            *(uint4*)(Bs + row * LDP + col8 * 8) =
                *(const uint4*)(Bt + (size_t)(n0 + row) * K + kb + col8 * 8);
        }
        __syncthreads();
        #pragma unroll
        for (int kk = 0; kk < 64; kk += 32) {
            bf16x8 af[2], bfv[2];
            #pragma unroll
            for (int mt = 0; mt < 2; mt++)
                af[mt] = *(const bf16x8*)(As + (wm * 32 + mt * 16 + l16) * LDP + kk + quad * 8);
            #pragma unroll
            for (int nt = 0; nt < 2; nt++)
                bfv[nt] = *(const bf16x8*)(Bs + (wn * 32 + nt * 16 + l16) * LDP + kk + quad * 8);
            #pragma unroll
            for (int mt = 0; mt < 2; mt++)
                #pragma unroll
                for (int nt = 0; nt < 2; nt++)
                    acc[mt][nt] = __builtin_amdgcn_mfma_f32_16x16x32_bf16(
                        af[mt], bfv[nt], acc[mt][nt], 0, 0, 0);
        }
        __syncthreads();
    }
    #pragma unroll
    for (int mt = 0; mt < 2; mt++) {
        #pragma unroll
        for (int nt = 0; nt < 2; nt++) {
            #pragma unroll
            for (int r = 0; r < 4; r++) {
                int mg = m0 + wm * 32 + mt * 16 + quad * 4 + r;
                int ng = n0 + wn * 32 + nt * 16 + l16;
                float v = acc[mt][nt][r] + bias[ng];
                if (RELU) v = fmaxf(v, 0.f);
                if (OUTBF) ((u16*)outv)[(size_t)mg * N + ng] = f2bf(v);
                else       ((float*)outv)[(size_t)mg * N + ng] = v;
            }
        }
    }
}

// ---------------------------------------------------------------------------
__global__ __launch_bounds__(256) void graph_tile(
    const float* __restrict__ low, const int* __restrict__ target,
    float* __restrict__ gpre, float* __restrict__ ggt)
{
    __shared__ float Al[64 * 132];
    __shared__ float Bl[128 * 68];
    const int t = threadIdx.x;
    const int gr0 = (blockIdx.x >> 3) * 64;
    const int gc0 = (blockIdx.x & 7) * 64;

    #pragma unroll
    for (int j = 0; j < 32; j++) {
        int flat = t + 256 * j;
        int k = flat & 127;
        int rc = flat >> 7;
        Al[rc * 132 + k] = low[(size_t)(gr0 + rc) * 128 + k];
        Bl[k * 68 + rc]  = low[(size_t)(gc0 + rc) * 128 + k];
    }
    __syncthreads();

    const int tx = t & 15, ty = t >> 4;
    float acc[4][4];
    #pragma unroll
    for (int r = 0; r < 4; r++)
        #pragma unroll
        for (int c = 0; c < 4; c++) acc[r][c] = 0.f;

    for (int k = 0; k < 128; k++) {
        float a[4], b[4];
        #pragma unroll
        for (int r = 0; r < 4; r++) a[r] = Al[(ty * 4 + r) * 132 + k];
        #pragma unroll
        for (int c = 0; c < 4; c++) b[c] = Bl[k * 68 + tx * 4 + c];
        #pragma unroll
        for (int r = 0; r < 4; r++)
            #pragma unroll
            for (int c = 0; c < 4; c++) acc[r][c] += a[r] * b[c];
    }
    #pragma unroll
    for (int r = 0; r < 4; r++) {
        int row = gr0 + ty * 4 + r;
        int tr  = target[row];
        float4 gp, gg;
        float* pp = (float*)&gp;
        float* gg_ = (float*)&gg;
        #pragma unroll
        for (int c = 0; c < 4; c++) {
            pp[c]  = 1.f / (1.f + __expf(-acc[r][c]));
            gg_[c] = (tr == target[gc0 + tx * 4 + c]) ? 1.f : 0.f;
        }
        *(float4*)(gpre + (size_t)row * 512 + gc0 + tx * 4) = gp;
        *(float4*)(ggt  + (size_t)row * 512 + gc0 + tx * 4) = gg;
    }
}

// ---------------------------------------------------------------------------
__global__ __launch_bounds__(256) void cls_kernel(
    const u16* __restrict__ feat, const float* __restrict__ w,
    const float* __restrict__ bias, float* __restrict__ out)
{
    __shared__ float ws[5120];
    const int t = threadIdx.x;
    for (int i = t; i < 5120; i += 256) ws[i] = w[i];
    __syncthreads();
    const int lane = t & 63;
    const int row  = blockIdx.x * 4 + (t >> 6);
    float a[10];
    #pragma unroll
    for (int j = 0; j < 10; j++) a[j] = 0.f;
    #pragma unroll
    for (int i = 0; i < 8; i++) {
        int k = i * 64 + lane;
        float f = bf2f(feat[(size_t)row * 512 + k]);
        #pragma unroll
        for (int j = 0; j < 10; j++) a[j] += f * ws[k * 10 + j];
    }
    #pragma unroll
    for (int j = 0; j < 10; j++)
        #pragma unroll
        for (int off = 32; off > 0; off >>= 1)
            a[j] += __shfl_down(a[j], off, 64);
    if (lane == 0) {
        #pragma unroll
        for (int j = 0; j < 10; j++) out[row * 10 + j] = a[j] + bias[j];
    }
}

// ---------------------------------------------------------------------------
extern "C" void kernel_launch(void* const* d_in, const int* in_sizes, int n_in,
                              void* d_out, int out_size, void* d_ws, size_t ws_size,
                              hipStream_t stream)
{
    const float* x      = (const float*)d_in[0];
    const int*   target = (const int*)d_in[1];
    const float* conv_w[13];
    const float* conv_b[13];
    for (int i = 0; i < 13; i++) {
        conv_w[i] = (const float*)d_in[2 + 2 * i];
        conv_b[i] = (const float*)d_in[3 + 2 * i];
    }
    const float* lin1_w = (const float*)d_in[28];
    const float* lin1_b = (const float*)d_in[29];
    const float* lin2_w = (const float*)d_in[30];
    const float* lin2_b = (const float*)d_in[31];
    const float* cls_w  = (const float*)d_in[32];
    const float* cls_b  = (const float*)d_in[33];
    float* out = (float*)d_out;

    static const int cin_arr[13]  = {3, 64, 64, 128, 128, 256, 256, 256, 512, 512, 512, 512, 512};
    static const int cout_arr[13] = {64, 64, 128, 128, 256, 256, 256, 512, 512, 512, 512, 512, 512};

    char* ws = (char*)d_ws;
    size_t off = 0;
    const size_t R0SZ = (size_t)512 * 34 * 34 * 64 * 2;
    const size_t R1SZ = (size_t)512 * 34 * 34 * 64 * 2;
    char* R0raw = ws + off; off += R0SZ;
    char* R1raw = ws + off; off += R1SZ;
    u16* R0 = (u16*)R0raw;
    u16* R1 = (u16*)R1raw;
    float* PA = (float*)(R0raw + 20971520);
    float* PB = (float*)(R1raw + 20971520);
    u16* wt[13];
    for (int i = 1; i < 13; i++) {
        wt[i] = (u16*)(ws + off);
        off += (size_t)cout_arr[i] * 9 * cin_arr[i] * 2;
    }
    u16* wtl1 = (u16*)(ws + off); off += (size_t)256 * 512 * 2;
    u16* wtl2 = (u16*)(ws + off); off += (size_t)128 * 256 * 2;
    u16* hbuf = (u16*)(ws + off); off += (size_t)512 * 256 * 2;
    float* lowbuf = (float*)(ws + off); off += (size_t)512 * 128 * 4;

    // ---- single merged repack launch (12 conv + 2 lin), LDS-staged ----
    RepackArgs ra;
    int nb = 0, blk = 0;
    ra.startBlk[0] = 0;
    for (int i = 1; i < 13; i++) {
        ra.src[nb] = conv_w[i];
        ra.dst[nb] = wt[i];
        ra.p1[nb] = cin_arr[i];
        ra.p2[nb] = 0;
        blk += cout_arr[i] * cin_arr[i] / 1024;   // 9216 elems per block
        nb++; ra.startBlk[nb] = blk;
    }
    ra.src[nb] = lin1_w; ra.dst[nb] = wtl1; ra.p1[nb] = 512; ra.p2[nb] = 256;
    blk += (512 / 64) * (256 / 64);
    nb++; ra.startBlk[nb] = blk;
    ra.src[nb] = lin2_w; ra.dst[nb] = wtl2; ra.p1[nb] = 256; ra.p2[nb] = 128;
    blk += (256 / 64) * (128 / 64);
    nb++; ra.startBlk[nb] = blk;
    ra.nseg = nb;
    repack_all<<<blk, 256, 0, stream>>>(ra);

    auto zh = [&](u16* buf, int Hp, int C) {
        int total8 = 512 * (4 * Hp - 4) * (C / 8);
        zero_halo<<<(total8 + 255) / 256, 256, 0, stream>>>(buf, Hp, C, total8);
    };
    auto launch_conv = [&](int li, int Hl, int bm, int bn, u16* inb, u16* outb,
                           float* part, int splitN, int outPad, int poolMode) {
        int Cin = cin_arr[li], Cout = cout_arr[li];
        int M = 512 * Hl * Hl;
        int logW = __builtin_ctz(Hl);
        int logHW = 2 * logW;
        size_t pstride = (size_t)M * Cout;
        int grid = (M / bm) * (Cout / bn) * splitN;
        if (bm == 256) {
            conv_gemm<256, 64><<<grid, 256, 0, stream>>>(
                inb, wt[li], conv_b[li], outb, part, pstride,
                Hl, Cin, Cout, logHW, logW, splitN, outPad, poolMode);
        } else if (bn == 128) {
            conv_gemm<128, 128><<<grid, 256, 0, stream>>>(
                inb, wt[li], conv_b[li], outb, part, pstride,
                Hl, Cin, Cout, logHW, logW, splitN, outPad, poolMode);
        } else {
            conv_gemm<128, 64><<<grid, 256, 0, stream>>>(
                inb, wt[li], conv_b[li], outb, part, pstride,
                Hl, Cin, Cout, logHW, logW, splitN, outPad, poolMode);
        }
    };
    auto launch_reduce = [&](int li, int Hl, u16* outb, float* part, int splitN, int outPad) {
        int Cout = cout_arr[li];
        int M = 512 * Hl * Hl;
        int logW = __builtin_ctz(Hl);
        size_t pstride = (size_t)M * Cout;
        int MN = M * Cout;
        reduce_split<<<(MN / 4 + 255) / 256, 256, 0, stream>>>(
            part, conv_b[li], outb, MN, Cout, __builtin_ctz(Cout),
            splitN, pstride, Hl, 2 * logW, logW, outPad);
    };
    auto launch_reduce_pool = [&](int li, int Hl, u16* outb, float* part, int splitN, int outPad) {
        int Cout = cout_arr[li];
        int M = 512 * Hl * Hl;
        size_t pstride = (size_t)M * Cout;
        int total4 = 512 * (Hl / 2) * (Hl / 2) * Cout / 4;
        reduce_pool<<<(total4 + 255) / 256, 256, 0, stream>>>(
            part, conv_b[li], outb, total4, Cout, splitN, pstride, Hl, outPad);
    };

    zh(R0, 34, 64);
    conv0_mfma<<<512 * 4, 256, 0, stream>>>(x, conv_w[0], conv_b[0], R0);

    zh(R1, 18, 64);
    conv_halo<256, 64, 32, 64><<<2048, 256, 0, stream>>>(
        R0, wt[1], conv_b[1], R1, 0, 1);                     // L1 + pool (halo)
    zh(R0, 18, 128);
    conv_halo<128, 128, 16, 64><<<1024, 256, 0, stream>>>(
        R1, wt[2], conv_b[2], R0, 1, 0);                     // L2 (halo)
    zh(R1, 10, 128);
    conv_halo<128, 128, 16, 128><<<1024, 256, 0, stream>>>(
        R0, wt[3], conv_b[3], R1, 0, 1);                     // L3 + pool (halo)
    zh(R0, 10, 256);
    launch_conv(4, 8, 128, 128, R1, R0, nullptr, 1, 1, 0);   // L4
    zh(R1, 10, 256);
    launch_conv(5, 8, 128, 128, R0, R1, nullptr, 1, 1, 0);   // L5
    zh(R0, 6, 256);
    launch_conv(6, 8, 128, 128, R1, R0, nullptr, 1, 0, 1);   // L6 + pool
    zh(R1, 6, 512);
    launch_conv(7, 4, 128, 128, R0, R1, PB, 2, 1, 0);        // L7 split2
    launch_reduce(7, 4, R1, PB, 2, 1);
    zh(R0, 6, 512);
    launch_conv(8, 4, 128, 128, R1, R0, PA, 2, 1, 0);        // L8 split2
    launch_reduce(8, 4, R0, PA, 2, 1);
    zh(R1, 4, 512);
    launch_conv(9, 4, 128, 128, R0, R1, PB, 2, 0, 0);        // L9 split2
    launch_reduce_pool(9, 4, R1, PB, 2, 1);
    zh(R0, 4, 512);
    launch_conv(10, 2, 128, 64, R1, R0, PA, 4, 1, 0);        // L10 split4
    launch_reduce(10, 2, R0, PA, 4, 1);
    zh(R1, 4, 512);
    launch_conv(11, 2, 128, 64, R0, R1, PB, 4, 1, 0);        // L11 split4
    launch_reduce(11, 2, R1, PB, 4, 1);
    launch_conv(12, 2, 128, 64, R1, R0, PA, 4, 0, 0);        // L12 split4
    launch_reduce_pool(12, 2, R0, PA, 4, 0);                 // feat = R0 [512,512]

    u16* feat = R0;
    gemm64<true, true><<<(512 / 64) * (256 / 64), 256, 0, stream>>>(
        feat, wtl1, lin1_b, hbuf, 512, 256, 512);
    gemm64<false, false><<<(512 / 64) * (128 / 64), 256, 0, stream>>>(
        hbuf, wtl2, lin2_b, lowbuf, 512, 128, 256);
    graph_tile<<<64, 256, 0, stream>>>(lowbuf, target, out + 5120, out + 5120 + 262144);
    cls_kernel<<<128, 256, 0, stream>>>(feat, cls_w, cls_b, out);
}